// Round 15
// baseline (610.753 us; speedup 1.0000x reference)
//
#include <hip/hip_runtime.h>

#define NPNT 4096
#define NSTK 32

typedef _Float16 half8 __attribute__((ext_vector_type(8)));
typedef float f32x4 __attribute__((ext_vector_type(4)));

// ---------------- workspace layout (floats) ----------------
static const size_t OFF_XT   = 0;          // XT2H/XT2L (f16) live here; E aliases later
static const size_t OFF_P    = 4194304;    // P' compact fp32 [b,16,128,256] = 2097152
static const size_t OFF_Q    = 8388608;    // Q' fp32 [b,n,256]; PDL/PIL alias before k_pq
static const size_t OFF_SQD  = 12582912;   // 16384
static const size_t OFF_SPFD = 12599296;   // 16384
static const size_t OFF_XS   = 12615680;   // 32768
static const size_t OFF_PS   = 12648448;   // 32768
static const size_t OFF_QS   = 12681216;   // 32768
static const size_t OFF_WSP  = 12746752;   // W f16 splits
static const size_t OFF_KNN  = 13402112;   // knnc compact 81920 (int)
static const size_t OFF_IDXS = 13565952;   // 256 (int)
static const size_t OFF_FPS  = 13566208;   // 64 (int)
static const size_t OFF_SD   = 13566272;   // 4096

__device__ __forceinline__ bool lexlt(float d1, int i1, float d2, int i2) {
  return (d1 < d2) || (d1 == d2 && i1 < i2);
}
__device__ __forceinline__ void insert10(float ld[10], int li[10], float d, int i) {
  if (!lexlt(d, i, ld[9], li[9])) return;
  ld[9] = d; li[9] = i;
#pragma unroll
  for (int j = 9; j > 0; j--) {
    if (lexlt(ld[j], li[j], ld[j-1], li[j-1])) {
      float td = ld[j]; ld[j] = ld[j-1]; ld[j-1] = td;
      int ti = li[j]; li[j] = li[j-1]; li[j-1] = ti;
    }
  }
}

// ---------------- K0e: fused transpose+broadcast+split+sqd ----------
__global__ __launch_bounds__(256) void k_split256(const float* __restrict__ df, const float* __restrict__ sf,
    _Float16* __restrict__ XH, _Float16* __restrict__ XL, float* __restrict__ sqd) {
  int b = blockIdx.x, n0 = blockIdx.y * 64;
  int t = threadIdx.x;
  int s0 = n0 >> 7;
  __shared__ float T[128][68];
  __shared__ _Float16 Sh[128], Sl[128];
  {
    int c = t >> 1, nh = (t & 1) * 32;
    const float* src = &df[((size_t)b * 128 + c) * NPNT + n0 + nh];
#pragma unroll
    for (int j = 0; j < 8; j++) *(float4*)&T[c][nh + j * 4] = *(const float4*)&src[j * 4];
  }
  if (t < 128) {
    float x = sf[((size_t)b * 128 + t) * NSTK + s0];
    _Float16 hi = (_Float16)x;
    Sh[t] = hi; Sl[t] = (_Float16)(x - (float)hi);
  }
  __syncthreads();
  {
    int n = t >> 2, cseg = (t & 3) * 32;
    size_t base = ((size_t)b * NPNT + n0 + n) * 256;
    float s = 0.0f;
#pragma unroll
    for (int k = 0; k < 4; k++) {
      half8 hv, lv, shv, slv;
#pragma unroll
      for (int e = 0; e < 8; e++) {
        float x = T[cseg + k * 8 + e][n];
        s = fmaf(x, x, s);
        _Float16 hi = (_Float16)x;
        hv[e] = hi; lv[e] = (_Float16)(x - (float)hi);
        shv[e] = Sh[cseg + k * 8 + e];
        slv[e] = Sl[cseg + k * 8 + e];
      }
      *(half8*)&XH[base + cseg + k * 8] = hv;
      *(half8*)&XL[base + cseg + k * 8] = lv;
      *(half8*)&XH[base + 128 + cseg + k * 8] = shv;
      *(half8*)&XL[base + 128 + cseg + k * 8] = slv;
    }
    s += __shfl_xor(s, 1);
    s += __shfl_xor(s, 2);
    if ((t & 3) == 0) sqd[(size_t)b * NPNT + n0 + n] = s;
  }
}

// ---------------- K0f: W split ----------------
__global__ __launch_bounds__(256) void k_splitW(const float* __restrict__ W,
    _Float16* __restrict__ WPh, _Float16* __restrict__ WPl,
    _Float16* __restrict__ WQh, _Float16* __restrict__ WQl) {
  int k = blockIdx.x, o = threadIdx.x;
  float w1 = W[(size_t)k * 256 + o];
  float w2 = W[(size_t)(k + 256) * 256 + o];
  float p = w1 - w2;
  _Float16 ph = (_Float16)p;  WPh[(size_t)o * 256 + k] = ph;
  WPl[(size_t)o * 256 + k] = (_Float16)(p - (float)ph);
  _Float16 qh = (_Float16)w2; WQh[(size_t)o * 256 + k] = qh;
  WQl[(size_t)o * 256 + k] = (_Float16)(w2 - (float)qh);
}

// ---------------- K1: DenseToSparse conv(1,3)+BN+ReLU+max ----------------
__global__ __launch_bounds__(256) void k_d2s(const float* __restrict__ df, const float* __restrict__ w,
    const float* __restrict__ cb, const float* __restrict__ g, const float* __restrict__ bt,
    float* __restrict__ spfd) {
  int b = blockIdx.x, o0 = blockIdx.y * 64, n0 = blockIdx.z * 64;
  int t = threadIdx.x;
  __shared__ float A[96][64];
  __shared__ float Bs[32][68];
  float acc[4][4];
#pragma unroll
  for (int i = 0; i < 4; i++)
#pragma unroll
    for (int j = 0; j < 4; j++) acc[i][j] = 0.0f;
  int tn = t & 15, to = t >> 4;
  for (int ic = 0; ic < 128; ic += 32) {
    {
      int ol = t >> 2, q = t & 3;
      const float* src = &w[((size_t)(o0 + ol) * 128 + ic) * 3 + q * 24];
#pragma unroll
      for (int r = 0; r < 6; r++) {
        float4 v = *(const float4*)&src[r * 4];
        int e = q * 24 + r * 4;
        A[e+0][ol] = v.x; A[e+1][ol] = v.y; A[e+2][ol] = v.z; A[e+3][ol] = v.w;
      }
    }
    for (int idx = t; idx < 32 * 17; idx += 256) {
      int row = idx / 17, f4 = idx % 17;
      int nb = n0 + f4 * 4;
      const float* srow = &df[((size_t)b * 128 + ic + row) * NPNT];
      float4 v;
      if (nb + 3 < NPNT) v = *(const float4*)&srow[nb];
      else {
        v.x = srow[nb   < NPNT ? nb   : NPNT-1];
        v.y = srow[nb+1 < NPNT ? nb+1 : NPNT-1];
        v.z = srow[nb+2 < NPNT ? nb+2 : NPNT-1];
        v.w = srow[nb+3 < NPNT ? nb+3 : NPNT-1];
      }
      *(float4*)&Bs[row][f4 * 4] = v;
    }
    __syncthreads();
#pragma unroll 2
    for (int ii = 0; ii < 32; ii++) {
      float bv[8];
      *(float4*)&bv[0] = *(const float4*)&Bs[ii][tn * 4];
      *(float4*)&bv[4] = *(const float4*)&Bs[ii][tn * 4 + 4];
#pragma unroll
      for (int kw = 0; kw < 3; kw++) {
        float4 av = *(const float4*)&A[ii * 3 + kw][to * 4];
#pragma unroll
        for (int j = 0; j < 4; j++) {
          float bvj = bv[kw + j];
          acc[0][j] = fmaf(av.x, bvj, acc[0][j]);
          acc[1][j] = fmaf(av.y, bvj, acc[1][j]);
          acc[2][j] = fmaf(av.z, bvj, acc[2][j]);
          acc[3][j] = fmaf(av.w, bvj, acc[3][j]);
        }
      }
    }
    __syncthreads();
  }
  int s = n0 >> 7;
#pragma unroll
  for (int i = 0; i < 4; i++) {
    int o = o0 + to * 4 + i;
    float gg = g[o], bb = cb[o], bo = bt[o];
    float m = 0.0f;
#pragma unroll
    for (int j = 0; j < 4; j++) {
      int n = n0 + tn * 4 + j;
      int p = n & 127;
      if (p < 126) {
        float v = fmaf(gg, acc[i][j] + bb, bo);
        v = v > 0.0f ? v : 0.0f;
        m = v > m ? v : m;
      }
    }
    atomicMax((int*)&spfd[((size_t)b * 128 + o) * NSTK + s], __float_as_int(m));
  }
}

// ---------------- K0d: SD[b][s][u] ----------------
__global__ __launch_bounds__(256) void k_sd(const float* __restrict__ sf, float* __restrict__ SD) {
  int b = blockIdx.x, t = threadIdx.x;
  __shared__ float X[32][132];
  for (int idx = t; idx < 128 * 32; idx += 256) {
    int c = idx >> 5, s = idx & 31;
    X[s][c] = sf[((size_t)b * 128 + c) * NSTK + s];
  }
  __syncthreads();
#pragma unroll
  for (int rep = 0; rep < 4; rep++) {
    int p = t + rep * 256;
    int s = p >> 5, u = p & 31;
    float acc = 0.0f;
    for (int c = 0; c < 128; c++) {
      float d = X[s][c] - X[u][c];
      acc = fmaf(d, d, acc);
    }
    SD[(size_t)b * 1024 + p] = acc;
  }
}

// ---------------- K2: FPS + out2 gather ----------------
__global__ __launch_bounds__(128) void k_fps(const float* __restrict__ coor, int* __restrict__ fpsidx,
                                             float* __restrict__ out2) {
  int b = blockIdx.x, t = threadIdx.x;
  __shared__ float X[32][132];
  __shared__ float dist[32];
  __shared__ int far_s;
  __shared__ int sel[16];
  for (int idx = t; idx < 32 * 32; idx += 128) {
    int r = idx >> 5, q = idx & 31;
    *(float4*)&X[r][q * 4] = *(const float4*)&coor[((size_t)b * 32 + r) * 128 + q * 4];
  }
  if (t < 32) dist[t] = 1e10f;
  if (t == 0) far_s = 0;
  __syncthreads();
  for (int it = 0; it < 16; it++) {
    int far = far_s;
    if (t == 0) sel[it] = far;
    if (t < 32) {
      float d = 0.0f;
      for (int c = 0; c < 128; c++) { float dd = X[t][c] - X[far][c]; d = fmaf(dd, dd, d); }
      float dm = dist[t];
      dist[t] = d < dm ? d : dm;
    }
    __syncthreads();
    if (t == 0) {
      float best = -1.0f; int bi = 0;
      for (int m = 0; m < 32; m++) if (dist[m] > best) { best = dist[m]; bi = m; }
      far_s = bi;
    }
    __syncthreads();
  }
  if (t < 16) fpsidx[b * 16 + t] = sel[t];
  __syncthreads();
  for (int idx = t; idx < 16 * 32; idx += 128) {
    int j = idx >> 5, q = idx & 31;
    *(float4*)&out2[((size_t)b * 16 + j) * 128 + q * 4] = *(const float4*)&X[sel[j]][q * 4];
  }
}

// ---------------- K3a: sparse graph ----------------
__global__ __launch_bounds__(256) void k_sparse_graph(const float* __restrict__ sf, const float* __restrict__ spfd,
    float* __restrict__ xs, int* __restrict__ idxs) {
  int b = blockIdx.x, t = threadIdx.x;
  __shared__ float X[32][260];
  __shared__ float sq[32];
  __shared__ float D[32][33];
  for (int idx = t; idx < 32 * 256; idx += 256) {
    int n = idx >> 8, c = idx & 255;
    float v = (c < 128) ? sf[((size_t)b * 128 + c) * NSTK + n]
                        : spfd[((size_t)b * 128 + (c - 128)) * NSTK + n];
    X[n][c] = v;
  }
  __syncthreads();
  for (int idx = t; idx < 32 * 64; idx += 256) {
    int n = idx >> 6, q = idx & 63;
    *(float4*)&xs[((size_t)b * 32 + n) * 256 + q * 4] = *(const float4*)&X[n][q * 4];
  }
  if (t < 32) {
    float s = 0.0f;
    for (int c = 0; c < 256; c++) s = fmaf(X[t][c], X[t][c], s);
    sq[t] = s;
  }
  __syncthreads();
  {
    int n = t >> 3;
    for (int mg = 0; mg < 4; mg++) {
      int m = (t & 7) + mg * 8;
      float dot = 0.0f;
      for (int c = 0; c < 256; c++) dot = fmaf(X[n][c], X[m][c], dot);
      D[n][m] = (sq[n] - 2.0f * dot) + sq[m];
    }
  }
  __syncthreads();
  if (t < 32) {
    float d0 = 1e30f, d1 = 1e30f; int i0 = 0, i1 = 0;
    for (int m = 0; m < 32; m++) {
      float d = D[t][m];
      if (d < d0) { d1 = d0; i1 = i0; d0 = d; i0 = m; }
      else if (d < d1) { d1 = d; i1 = m; }
    }
    idxs[(b * 32 + t) * 2 + 0] = i0;
    idxs[(b * 32 + t) * 2 + 1] = i1;
  }
}

// ---------------- K3b: sparse P/Q ----------------
__global__ __launch_bounds__(256) void k_sparse_pq(const float* __restrict__ xs, const float* __restrict__ W,
    float* __restrict__ Ps, float* __restrict__ Qs) {
  int b = blockIdx.x >> 5, n = blockIdx.x & 31;
  int o = threadIdx.x;
  const float* xr = &xs[((size_t)b * 32 + n) * 256];
  float accP = 0.0f, accQ = 0.0f;
  for (int c = 0; c < 256; c++) {
    float xc = xr[c];
    float w1 = W[(size_t)c * 256 + o];
    float w2 = W[(size_t)(c + 256) * 256 + o];
    accP = fmaf(xc, w1 - w2, accP);
    accQ = fmaf(xc, w2, accQ);
  }
  Ps[((size_t)b * 32 + n) * 256 + o] = accP;
  Qs[((size_t)b * 32 + n) * 256 + o] = accQ;
}

// ---------------- K3c: combine+gather fused ----------------
__global__ __launch_bounds__(256) void k_sparse_cg(const float* __restrict__ Ps, const float* __restrict__ Qs,
    const int* __restrict__ idxs, const int* __restrict__ fps,
    const float* __restrict__ g, const float* __restrict__ cb, const float* __restrict__ bt,
    float* __restrict__ out0) {
  int b = blockIdx.x, j = blockIdx.y, o = threadIdx.x;
  int n = fps[b * 16 + j];
  int i0 = idxs[(b * 32 + n) * 2 + 0], i1 = idxs[(b * 32 + n) * 2 + 1];
  float p = Ps[((size_t)b * 32 + n) * 256 + o];
  float q0 = Qs[((size_t)b * 32 + i0) * 256 + o];
  float q1 = Qs[((size_t)b * 32 + i1) * 256 + o];
  float gg = g[o], bb = cb[o], bo = bt[o];
  float h0 = fmaf(gg, p + q0 + bb, bo); h0 = h0 > 0.0f ? h0 : 0.0f;
  float h1 = fmaf(gg, p + q1 + bb, bo); h1 = h1 > 0.0f ? h1 : 0.0f;
  out0[((size_t)b * 256 + o) * 16 + j] = h0 > h1 ? h0 : h1;
}

// ---------------- K4: dense kNN — ONLY FPS-selected rows (2048/batch), compact output -----
// grid (2, 32, 4): m-half, compact rowblock(64 rows = 4 waves x 16), b. 256 blocks.
// rb -> stroke slot jst=rb>>1, offset ph=(rb&1)*64; source rows fps[b,jst]*128+ph+...
#define STAGE(p_) { \
  float4 gh[4], gl[4]; \
  _Pragma("unroll") \
  for (int j = 0; j < 4; j++) { \
    size_t gp = (bofs + (size_t)(m0 + j * 32 + sm0)) * 256 + (p_) * 64 + sk8 * 8; \
    gh[j] = *(const float4*)&XH[gp]; gl[j] = *(const float4*)&XL[gp]; } \
  _Pragma("unroll") \
  for (int j = 0; j < 4; j++) { \
    int lo = (j * 32 + sm0) * 72 + sk8 * 8; \
    *(float4*)&BshH[lo] = gh[j]; *(float4*)&BshL[lo] = gl[j]; } }

__global__ __launch_bounds__(256, 2) void k_knn_mfma(const _Float16* __restrict__ XH,
    const _Float16* __restrict__ XL, const float* __restrict__ sqd, const float* __restrict__ SD,
    const int* __restrict__ fps, float* __restrict__ pd, int* __restrict__ pi) {
  const int h = blockIdx.x, rb = blockIdx.y, b = blockIdx.z;
  const int t = threadIdx.x;
  const int w = t >> 6, L = t & 63;
  const int c15 = L & 15, q = L >> 4;
  const int jst = rb >> 1;
  const int ph = (rb & 1) * 64;
  const int s_stk = fps[b * 16 + jst];
  const int nsrc = s_stk * 128 + ph + w * 16;   // source rows for this wave
  const int rc0 = rb * 64 + w * 16;             // compact output row base
  const size_t bofs = (size_t)b * NPNT;

  __shared__ _Float16 BshH[128 * 72];
  __shared__ _Float16 BshL[128 * 72];
  __shared__ float Dw[4][16][132];
  __shared__ float tauW[4][16][4];

  const int sm0 = t >> 3;
  const int sk8 = t & 7;

  half8 ah[4], al[4];
  {
    const _Float16* ap  = XH + (bofs + nsrc + c15) * 256 + q * 8;
    const _Float16* apl = XL + (bofs + nsrc + c15) * 256 + q * 8;
#pragma unroll
    for (int ch = 0; ch < 4; ch++) {
      ah[ch] = *(const half8*)(ap + ch * 32);
      al[ch] = *(const half8*)(apl + ch * 32);
    }
  }
  float snr[4];
#pragma unroll
  for (int r = 0; r < 4; r++) snr[r] = sqd[bofs + nsrc + q * 4 + r];

  float ld[10]; int li[10];
#pragma unroll
  for (int j = 0; j < 10; j++) { ld[j] = 1e30f; li[j] = 0x7fffffff; }

  const bool own_here = ((s_stk >> 4) == h);
  const int r_sel = L >> 2, sl = L & 3;
  float tauR = 1e30f;

  int u = own_here ? s_stk : (h * 16);
  int m0 = u * 128;

#pragma unroll 1
  for (int it = 0; it < 16; it++) {
    int u_next = (it == 0) ? (h * 16 + (own_here ? 0 : 1)) : (u + 1);
    if (own_here && u_next == s_stk) u_next++;

    const float SDv = SD[((size_t)b * 32 + s_stk) * 32 + u];
    float smv[8];
#pragma unroll
    for (int cg = 0; cg < 8; cg++) smv[cg] = sqd[bofs + m0 + cg * 16 + c15];

    f32x4 zz = {0.0f, 0.0f, 0.0f, 0.0f};
    f32x4 acc[8];
#pragma unroll
    for (int cg = 0; cg < 8; cg++) acc[cg] = zz;

    __syncthreads();
    STAGE(0);
    __syncthreads();
#pragma unroll
    for (int chl = 0; chl < 2; chl++) {
#pragma unroll
      for (int cg = 0; cg < 8; cg++) {
        int lo = (cg * 16 + c15) * 72 + chl * 32 + q * 8;
        half8 bh = *(const half8*)&BshH[lo];
        half8 bl = *(const half8*)&BshL[lo];
        acc[cg] = __builtin_amdgcn_mfma_f32_16x16x32_f16(ah[chl], bh, acc[cg], 0, 0, 0);
        acc[cg] = __builtin_amdgcn_mfma_f32_16x16x32_f16(ah[chl], bl, acc[cg], 0, 0, 0);
        acc[cg] = __builtin_amdgcn_mfma_f32_16x16x32_f16(al[chl], bh, acc[cg], 0, 0, 0);
      }
    }
    __syncthreads();
    STAGE(1);
    __syncthreads();
#pragma unroll
    for (int chl = 0; chl < 2; chl++) {
#pragma unroll
      for (int cg = 0; cg < 8; cg++) {
        int lo = (cg * 16 + c15) * 72 + chl * 32 + q * 8;
        half8 bh = *(const half8*)&BshH[lo];
        half8 bl = *(const half8*)&BshL[lo];
        acc[cg] = __builtin_amdgcn_mfma_f32_16x16x32_f16(ah[2 + chl], bh, acc[cg], 0, 0, 0);
        acc[cg] = __builtin_amdgcn_mfma_f32_16x16x32_f16(ah[2 + chl], bl, acc[cg], 0, 0, 0);
        acc[cg] = __builtin_amdgcn_mfma_f32_16x16x32_f16(al[2 + chl], bh, acc[cg], 0, 0, 0);
      }
    }

#pragma unroll
    for (int cg = 0; cg < 8; cg++) {
      float basec = SDv + smv[cg];
#pragma unroll
      for (int r = 0; r < 4; r++)
        Dw[w][q * 4 + r][cg * 16 + c15] = snr[r] + basec - 2.0f * acc[cg][r];
    }
    if (it == 0) {
#pragma unroll
      for (int jj = 0; jj < 8; jj++) {
        float4 dv = *(const float4*)&Dw[w][r_sel][jj * 16 + sl * 4];
        int ib = m0 + jj * 16 + sl * 4;
        insert10(ld, li, dv.x, ib + 0);
        insert10(ld, li, dv.y, ib + 1);
        insert10(ld, li, dv.z, ib + 2);
        insert10(ld, li, dv.w, ib + 3);
      }
    } else {
      bool any = false;
#pragma unroll
      for (int jj = 0; jj < 8; jj++) {
        float4 dv = *(const float4*)&Dw[w][r_sel][jj * 16 + sl * 4];
        any = any || (dv.x <= tauR) || (dv.y <= tauR) || (dv.z <= tauR) || (dv.w <= tauR);
      }
      if (any) {
#pragma unroll
        for (int jj = 0; jj < 8; jj++) {
          float4 dv = *(const float4*)&Dw[w][r_sel][jj * 16 + sl * 4];
          int ib = m0 + jj * 16 + sl * 4;
          if (dv.x <= tauR) insert10(ld, li, dv.x, ib + 0);
          if (dv.y <= tauR) insert10(ld, li, dv.y, ib + 1);
          if (dv.z <= tauR) insert10(ld, li, dv.z, ib + 2);
          if (dv.w <= tauR) insert10(ld, li, dv.w, ib + 3);
        }
      }
    }
    tauW[w][r_sel][sl] = ld[9];
    float4 tv = *(const float4*)&tauW[w][r_sel][0];
    tauR = fminf(fminf(tv.x, tv.y), fminf(tv.z, tv.w));

    u = u_next; m0 = u_next * 128;
  }

#pragma unroll
  for (int j = 0; j < 10; j++) {
    Dw[w][r_sel][sl * 10 + j] = ld[j];
    Dw[w][r_sel][40 + sl * 10 + j] = __int_as_float(li[j]);
  }
  if (L < 16) {
    float fd[10]; int fi[10];
#pragma unroll
    for (int j = 0; j < 10; j++) { fd[j] = 1e30f; fi[j] = 0x7fffffff; }
    for (int x = 0; x < 40; x++)
      insert10(fd, fi, Dw[w][L][x], __float_as_int(Dw[w][L][40 + x]));
    size_t row = (size_t)b * 2048 + rc0 + L;   // compact row
#pragma unroll
    for (int j = 0; j < 10; j++) {
      pd[(row * 2 + h) * 10 + j] = fd[j];
      pi[(row * 2 + h) * 10 + j] = fi[j];
    }
  }
}

// ---------------- K4b: merge the 2 half-lists (compact rows) ----------------
__global__ __launch_bounds__(256) void k_knn_merge(const float* __restrict__ pd, const int* __restrict__ pi,
                                                   int* __restrict__ knnc) {
  size_t row = blockIdx.x * 256 + threadIdx.x;   // 32 blocks: 8192 compact rows
  float ld[10]; int li[10];
#pragma unroll
  for (int jj = 0; jj < 10; jj++) { ld[jj] = pd[row * 20 + jj]; li[jj] = pi[row * 20 + jj]; }
#pragma unroll
  for (int jj = 0; jj < 10; jj++) insert10(ld, li, pd[row * 20 + 10 + jj], pi[row * 20 + 10 + jj]);
#pragma unroll
  for (int jj = 0; jj < 10; jj++) knnc[row * 10 + jj] = li[jj];
}

// ---------------- K5: Q' = g*Q for all rows; P' = g*(P+cb)+bt only for FPS rows ----------
__global__ __launch_bounds__(256, 2) void k_pq_mfma(const _Float16* __restrict__ XH, const _Float16* __restrict__ XL,
    const _Float16* __restrict__ WPh, const _Float16* __restrict__ WPl,
    const _Float16* __restrict__ WQh, const _Float16* __restrict__ WQl,
    const int* __restrict__ fps, const float* __restrict__ g, const float* __restrict__ cb,
    const float* __restrict__ bt, float* __restrict__ Pc, float* __restrict__ Qp) {
  const int b = blockIdx.z;
  const int t = threadIdx.x, w = t >> 6, L = t & 63;
  const int c15 = L & 15, q = L >> 4;
  const int ow = blockIdx.y * 128 + (w >> 1) * 64;
  const size_t bofs = (size_t)b * NPNT;
  f32x4 zz = {0.0f, 0.0f, 0.0f, 0.0f};

  {
    const int nw = blockIdx.x * 32 + (w & 1) * 16;
    f32x4 accQ[4];
#pragma unroll
    for (int cg = 0; cg < 4; cg++) accQ[cg] = zz;
    const _Float16* ap  = XH + (bofs + nw + c15) * 256 + q * 8;
    const _Float16* apl = XL + (bofs + nw + c15) * 256 + q * 8;
#pragma unroll
    for (int ch = 0; ch < 8; ch++) {
      half8 a_h = *(const half8*)(ap + ch * 32);
      half8 a_l = *(const half8*)(apl + ch * 32);
#pragma unroll
      for (int cg = 0; cg < 4; cg++) {
        size_t wb = (size_t)(ow + cg * 16 + c15) * 256 + ch * 32 + q * 8;
        half8 bqh = *(const half8*)(WQh + wb);
        half8 bql = *(const half8*)(WQl + wb);
        accQ[cg] = __builtin_amdgcn_mfma_f32_16x16x32_f16(a_h, bqh, accQ[cg], 0, 0, 0);
        accQ[cg] = __builtin_amdgcn_mfma_f32_16x16x32_f16(a_h, bql, accQ[cg], 0, 0, 0);
        accQ[cg] = __builtin_amdgcn_mfma_f32_16x16x32_f16(a_l, bqh, accQ[cg], 0, 0, 0);
      }
    }
#pragma unroll
    for (int cg = 0; cg < 4; cg++) {
      int o = ow + cg * 16 + c15;
      float gg = g[o];
#pragma unroll
      for (int r = 0; r < 4; r++) {
        Qp[(bofs + nw + q * 4 + r) * 256 + o] = gg * accQ[cg][r];
      }
    }
  }

  if (blockIdx.x < 64) {
    const int m0 = blockIdx.x * 32 + (w & 1) * 16;
    const int jst = m0 >> 7;
    const int pbase = m0 & 127;
    const int nsrc = fps[b * 16 + jst] * 128 + pbase;
    f32x4 accP[4];
#pragma unroll
    for (int cg = 0; cg < 4; cg++) accP[cg] = zz;
    const _Float16* ap  = XH + (bofs + nsrc + c15) * 256 + q * 8;
    const _Float16* apl = XL + (bofs + nsrc + c15) * 256 + q * 8;
#pragma unroll
    for (int ch = 0; ch < 8; ch++) {
      half8 a_h = *(const half8*)(ap + ch * 32);
      half8 a_l = *(const half8*)(apl + ch * 32);
#pragma unroll
      for (int cg = 0; cg < 4; cg++) {
        size_t wb = (size_t)(ow + cg * 16 + c15) * 256 + ch * 32 + q * 8;
        half8 bph = *(const half8*)(WPh + wb);
        half8 bpl = *(const half8*)(WPl + wb);
        accP[cg] = __builtin_amdgcn_mfma_f32_16x16x32_f16(a_h, bph, accP[cg], 0, 0, 0);
        accP[cg] = __builtin_amdgcn_mfma_f32_16x16x32_f16(a_h, bpl, accP[cg], 0, 0, 0);
        accP[cg] = __builtin_amdgcn_mfma_f32_16x16x32_f16(a_l, bph, accP[cg], 0, 0, 0);
      }
    }
#pragma unroll
    for (int cg = 0; cg < 4; cg++) {
      int o = ow + cg * 16 + c15;
      float gg = g[o], bb = cb[o], bo = bt[o];
#pragma unroll
      for (int r = 0; r < 4; r++) {
        Pc[(((size_t)b * 16 + jst) * 128 + pbase + q * 4 + r) * 256 + o] =
            fmaf(gg, accP[cg][r] + bb, bo);
      }
    }
  }
}

// ---------------- K6: build im2col E from compact P'/knnc + Q' ----------------
__global__ __launch_bounds__(256) void k_build_E(const float* __restrict__ Pc, const float* __restrict__ Qp,
    const int* __restrict__ knnc, float* __restrict__ E) {
  int pp = blockIdx.x, j = blockIdx.y, b = blockIdx.z;
  int t = threadIdx.x;
  float v[3];
#pragma unroll
  for (int dp = 0; dp < 3; dp++) {
    int p = 2 * pp - 1 + dp;
    float val = 0.0f;
    if (p >= 0 && p < 128) {
      size_t m = ((size_t)b * 16 + j) * 128 + p;
      float pv = Pc[m * 256 + t];
      const int* id = &knnc[m * 10];
      float mx = 0.0f;
#pragma unroll
      for (int k = 0; k < 10; k++) {
        float qv = Qp[((size_t)b * NPNT + id[k]) * 256 + t];
        float h = pv + qv;
        mx = h > mx ? h : mx;
      }
      val = mx;
    }
    v[dp] = val;
  }
  size_t base = ((size_t)(b * 16 + j) * 64 + pp) * 768;
  E[base + 3 * t + 0] = v[0];
  E[base + 3 * t + 1] = v[1];
  E[base + 3 * t + 2] = v[2];
}

// ---------------- K7: downsample GEMM ----------------
__global__ __launch_bounds__(256) void k_ds_gemm(const float* __restrict__ Wd, const float* __restrict__ E,
    const float* __restrict__ cb, const float* __restrict__ g, const float* __restrict__ bt,
    float* __restrict__ out1) {
  int j0 = blockIdx.x * 64, o0 = blockIdx.y * 64, b = blockIdx.z;
  int t = threadIdx.x;
  __shared__ float A[32][68];
  __shared__ float Bs[32][68];
  float acc[4][4];
#pragma unroll
  for (int i = 0; i < 4; i++)
#pragma unroll
    for (int j = 0; j < 4; j++) acc[i][j] = 0.0f;
  int tj = t & 15, to = t >> 4;
  for (int kc = 0; kc < 768; kc += 32) {
    {
      int ol = t >> 2, q = t & 3;
      const float* src = &Wd[(size_t)(o0 + ol) * 768 + kc + q * 8];
      float4 v0 = *(const float4*)src, v1 = *(const float4*)(src + 4);
      int cc = q * 8;
      A[cc+0][ol] = v0.x; A[cc+1][ol] = v0.y; A[cc+2][ol] = v0.z; A[cc+3][ol] = v0.w;
      A[cc+4][ol] = v1.x; A[cc+5][ol] = v1.y; A[cc+6][ol] = v1.z; A[cc+7][ol] = v1.w;
    }
    {
      int jl = t >> 2, q = t & 3;
      const float* src = &E[((size_t)b * 1024 + j0 + jl) * 768 + kc + q * 8];
      float4 v0 = *(const float4*)src, v1 = *(const float4*)(src + 4);
      int cc = q * 8;
      Bs[cc+0][jl] = v0.x; Bs[cc+1][jl] = v0.y; Bs[cc+2][jl] = v0.z; Bs[cc+3][jl] = v0.w;
      Bs[cc+4][jl] = v1.x; Bs[cc+5][jl] = v1.y; Bs[cc+6][jl] = v1.z; Bs[cc+7][jl] = v1.w;
    }
    __syncthreads();
#pragma unroll 4
    for (int k = 0; k < 32; k++) {
      float4 a = *(const float4*)&A[k][to * 4];
      float4 bv = *(const float4*)&Bs[k][tj * 4];
      float av[4] = {a.x, a.y, a.z, a.w};
      float bb[4] = {bv.x, bv.y, bv.z, bv.w};
#pragma unroll
      for (int i = 0; i < 4; i++)
#pragma unroll
        for (int j = 0; j < 4; j++)
          acc[i][j] = fmaf(av[i], bb[j], acc[i][j]);
    }
    __syncthreads();
  }
#pragma unroll
  for (int i = 0; i < 4; i++) {
    int o = o0 + to * 4 + i;
    float gg = g[o], bb = cb[o], bo = bt[o];
    float4 v;
    float x0 = fmaf(gg, acc[i][0] + bb, bo); v.x = x0 > 0.0f ? x0 : 0.0f;
    float x1 = fmaf(gg, acc[i][1] + bb, bo); v.y = x1 > 0.0f ? x1 : 0.0f;
    float x2 = fmaf(gg, acc[i][2] + bb, bo); v.z = x2 > 0.0f ? x2 : 0.0f;
    float x3 = fmaf(gg, acc[i][3] + bb, bo); v.w = x3 > 0.0f ? x3 : 0.0f;
    *(float4*)&out1[((size_t)b * 256 + o) * 1024 + j0 + tj * 4] = v;
  }
}

extern "C" void kernel_launch(void* const* d_in, const int* in_sizes, int n_in,
                              void* d_out, int out_size, void* d_ws, size_t ws_size,
                              hipStream_t stream) {
  (void)in_sizes; (void)n_in; (void)out_size; (void)ws_size;
  const float* sf    = (const float*)d_in[0];
  const float* df    = (const float*)d_in[1];
  const float* coor  = (const float*)d_in[2];
  const float* d2sw  = (const float*)d_in[3];
  const float* d2sb  = (const float*)d_in[4];
  const float* d2sg  = (const float*)d_in[5];
  const float* d2sbt = (const float*)d_in[6];
  const float* spW   = (const float*)d_in[7];
  const float* spb   = (const float*)d_in[8];
  const float* spg   = (const float*)d_in[9];
  const float* spbt  = (const float*)d_in[10];
  const float* dnW   = (const float*)d_in[11];
  const float* dnb   = (const float*)d_in[12];
  const float* dng   = (const float*)d_in[13];
  const float* dnbt  = (const float*)d_in[14];
  const float* dsw   = (const float*)d_in[15];
  const float* dsb   = (const float*)d_in[16];
  const float* dsg   = (const float*)d_in[17];
  const float* dsbt  = (const float*)d_in[18];

  float* ws   = (float*)d_ws;
  float* Pc   = ws + OFF_P;
  float* Qp   = ws + OFF_Q;
  float* SQD  = ws + OFF_SQD;
  float* SPFD = ws + OFF_SPFD;
  float* XS   = ws + OFF_XS;
  float* PS   = ws + OFF_PS;
  float* QS   = ws + OFF_QS;
  int*   KNNC = (int*)(ws + OFF_KNN);
  int*   IDXS = (int*)(ws + OFF_IDXS);
  int*   FPS  = (int*)(ws + OFF_FPS);
  float* SD   = ws + OFF_SD;
  _Float16* XT2H = (_Float16*)(ws + OFF_XT);
  _Float16* XT2L = XT2H + (size_t)4 * NPNT * 256;
  float* E = ws + OFF_XT;
  _Float16* WPh = (_Float16*)(ws + OFF_WSP);
  _Float16* WPl = WPh + 65536;
  _Float16* WQh = WPh + 131072;
  _Float16* WQl = WPh + 196608;
  // compact half-lists alias the Q region (consumed before k_pq_mfma writes Q')
  float* PDL = ws + OFF_Q;
  int*   PIL = (int*)(ws + OFF_Q + 163840);

  float* out0 = (float*)d_out;
  float* out1 = out0 + 16384;
  float* out2 = out1 + 1048576;

  hipMemsetAsync(SPFD, 0, 16384 * sizeof(float), stream);

  k_split256<<<dim3(4, 64), 256, 0, stream>>>(df, sf, XT2H, XT2L, SQD);
  k_splitW<<<dim3(256), 256, 0, stream>>>(dnW, WPh, WPl, WQh, WQl);
  k_d2s<<<dim3(4, 2, 64), 256, 0, stream>>>(df, d2sw, d2sb, d2sg, d2sbt, SPFD);
  k_sd<<<dim3(4), 256, 0, stream>>>(sf, SD);
  k_fps<<<dim3(4), 128, 0, stream>>>(coor, FPS, out2);
  k_sparse_graph<<<dim3(4), 256, 0, stream>>>(sf, SPFD, XS, IDXS);
  k_sparse_pq<<<dim3(128), 256, 0, stream>>>(XS, spW, PS, QS);
  k_sparse_cg<<<dim3(4, 16), 256, 0, stream>>>(PS, QS, IDXS, FPS, spg, spb, spbt, out0);
  k_knn_mfma<<<dim3(2, 32, 4), 256, 0, stream>>>(XT2H, XT2L, SQD, SD, FPS, PDL, PIL);
  k_knn_merge<<<dim3(32), 256, 0, stream>>>(PDL, PIL, KNNC);
  k_pq_mfma<<<dim3(128, 2, 4), 256, 0, stream>>>(XT2H, XT2L, WPh, WPl, WQh, WQl,
                                                 FPS, dng, dnb, dnbt, Pc, Qp);
  k_build_E<<<dim3(64, 16, 4), 256, 0, stream>>>(Pc, Qp, KNNC, E);
  k_ds_gemm<<<dim3(16, 4, 4), 256, 0, stream>>>(dsw, E, dsb, dsg, dsbt, out1);
}

// Round 16
// 525.275 us; speedup vs baseline: 1.1627x; 1.1627x over previous
//
#include <hip/hip_runtime.h>

#define NPNT 4096
#define NSTK 32

typedef _Float16 half8 __attribute__((ext_vector_type(8)));
typedef float f32x4 __attribute__((ext_vector_type(4)));

// ---------------- workspace layout (floats) ----------------
static const size_t OFF_XT   = 0;          // XT2H/XT2L (f16) live here; E aliases later
static const size_t OFF_P    = 4194304;    // P' compact fp32 [b,16,128,256] = 2097152
static const size_t OFF_Q    = 8388608;    // Q' fp32 [b,n,256]; PDL/PIL alias before k_pq
static const size_t OFF_SQD  = 12582912;   // 16384
static const size_t OFF_SPFD = 12599296;   // 16384
static const size_t OFF_XS   = 12615680;   // 32768
static const size_t OFF_PS   = 12648448;   // 32768
static const size_t OFF_QS   = 12681216;   // 32768
static const size_t OFF_WSP  = 12746752;   // W f16 splits
static const size_t OFF_KNN  = 13402112;   // knnc compact 81920 (int)
static const size_t OFF_IDXS = 13565952;   // 256 (int)
static const size_t OFF_FPS  = 13566208;   // 64 (int)
static const size_t OFF_SD   = 13566272;   // 4096

__device__ __forceinline__ bool lexlt(float d1, int i1, float d2, int i2) {
  return (d1 < d2) || (d1 == d2 && i1 < i2);
}
__device__ __forceinline__ void insert10(float ld[10], int li[10], float d, int i) {
  if (!lexlt(d, i, ld[9], li[9])) return;
  ld[9] = d; li[9] = i;
#pragma unroll
  for (int j = 9; j > 0; j--) {
    if (lexlt(ld[j], li[j], ld[j-1], li[j-1])) {
      float td = ld[j]; ld[j] = ld[j-1]; ld[j-1] = td;
      int ti = li[j]; li[j] = li[j-1]; li[j-1] = ti;
    }
  }
}

// ---------------- K0e: fused transpose+broadcast+split+sqd ----------
__global__ __launch_bounds__(256) void k_split256(const float* __restrict__ df, const float* __restrict__ sf,
    _Float16* __restrict__ XH, _Float16* __restrict__ XL, float* __restrict__ sqd) {
  int b = blockIdx.x, n0 = blockIdx.y * 64;
  int t = threadIdx.x;
  int s0 = n0 >> 7;
  __shared__ float T[128][68];
  __shared__ _Float16 Sh[128], Sl[128];
  {
    int c = t >> 1, nh = (t & 1) * 32;
    const float* src = &df[((size_t)b * 128 + c) * NPNT + n0 + nh];
#pragma unroll
    for (int j = 0; j < 8; j++) *(float4*)&T[c][nh + j * 4] = *(const float4*)&src[j * 4];
  }
  if (t < 128) {
    float x = sf[((size_t)b * 128 + t) * NSTK + s0];
    _Float16 hi = (_Float16)x;
    Sh[t] = hi; Sl[t] = (_Float16)(x - (float)hi);
  }
  __syncthreads();
  {
    int n = t >> 2, cseg = (t & 3) * 32;
    size_t base = ((size_t)b * NPNT + n0 + n) * 256;
    float s = 0.0f;
#pragma unroll
    for (int k = 0; k < 4; k++) {
      half8 hv, lv, shv, slv;
#pragma unroll
      for (int e = 0; e < 8; e++) {
        float x = T[cseg + k * 8 + e][n];
        s = fmaf(x, x, s);
        _Float16 hi = (_Float16)x;
        hv[e] = hi; lv[e] = (_Float16)(x - (float)hi);
        shv[e] = Sh[cseg + k * 8 + e];
        slv[e] = Sl[cseg + k * 8 + e];
      }
      *(half8*)&XH[base + cseg + k * 8] = hv;
      *(half8*)&XL[base + cseg + k * 8] = lv;
      *(half8*)&XH[base + 128 + cseg + k * 8] = shv;
      *(half8*)&XL[base + 128 + cseg + k * 8] = slv;
    }
    s += __shfl_xor(s, 1);
    s += __shfl_xor(s, 2);
    if ((t & 3) == 0) sqd[(size_t)b * NPNT + n0 + n] = s;
  }
}

// ---------------- K0f: W split ----------------
__global__ __launch_bounds__(256) void k_splitW(const float* __restrict__ W,
    _Float16* __restrict__ WPh, _Float16* __restrict__ WPl,
    _Float16* __restrict__ WQh, _Float16* __restrict__ WQl) {
  int k = blockIdx.x, o = threadIdx.x;
  float w1 = W[(size_t)k * 256 + o];
  float w2 = W[(size_t)(k + 256) * 256 + o];
  float p = w1 - w2;
  _Float16 ph = (_Float16)p;  WPh[(size_t)o * 256 + k] = ph;
  WPl[(size_t)o * 256 + k] = (_Float16)(p - (float)ph);
  _Float16 qh = (_Float16)w2; WQh[(size_t)o * 256 + k] = qh;
  WQl[(size_t)o * 256 + k] = (_Float16)(w2 - (float)qh);
}

// ---------------- K1: DenseToSparse conv(1,3)+BN+ReLU+max ----------------
__global__ __launch_bounds__(256) void k_d2s(const float* __restrict__ df, const float* __restrict__ w,
    const float* __restrict__ cb, const float* __restrict__ g, const float* __restrict__ bt,
    float* __restrict__ spfd) {
  int b = blockIdx.x, o0 = blockIdx.y * 64, n0 = blockIdx.z * 64;
  int t = threadIdx.x;
  __shared__ float A[96][64];
  __shared__ float Bs[32][68];
  float acc[4][4];
#pragma unroll
  for (int i = 0; i < 4; i++)
#pragma unroll
    for (int j = 0; j < 4; j++) acc[i][j] = 0.0f;
  int tn = t & 15, to = t >> 4;
  for (int ic = 0; ic < 128; ic += 32) {
    {
      int ol = t >> 2, q = t & 3;
      const float* src = &w[((size_t)(o0 + ol) * 128 + ic) * 3 + q * 24];
#pragma unroll
      for (int r = 0; r < 6; r++) {
        float4 v = *(const float4*)&src[r * 4];
        int e = q * 24 + r * 4;
        A[e+0][ol] = v.x; A[e+1][ol] = v.y; A[e+2][ol] = v.z; A[e+3][ol] = v.w;
      }
    }
    for (int idx = t; idx < 32 * 17; idx += 256) {
      int row = idx / 17, f4 = idx % 17;
      int nb = n0 + f4 * 4;
      const float* srow = &df[((size_t)b * 128 + ic + row) * NPNT];
      float4 v;
      if (nb + 3 < NPNT) v = *(const float4*)&srow[nb];
      else {
        v.x = srow[nb   < NPNT ? nb   : NPNT-1];
        v.y = srow[nb+1 < NPNT ? nb+1 : NPNT-1];
        v.z = srow[nb+2 < NPNT ? nb+2 : NPNT-1];
        v.w = srow[nb+3 < NPNT ? nb+3 : NPNT-1];
      }
      *(float4*)&Bs[row][f4 * 4] = v;
    }
    __syncthreads();
#pragma unroll 2
    for (int ii = 0; ii < 32; ii++) {
      float bv[8];
      *(float4*)&bv[0] = *(const float4*)&Bs[ii][tn * 4];
      *(float4*)&bv[4] = *(const float4*)&Bs[ii][tn * 4 + 4];
#pragma unroll
      for (int kw = 0; kw < 3; kw++) {
        float4 av = *(const float4*)&A[ii * 3 + kw][to * 4];
#pragma unroll
        for (int j = 0; j < 4; j++) {
          float bvj = bv[kw + j];
          acc[0][j] = fmaf(av.x, bvj, acc[0][j]);
          acc[1][j] = fmaf(av.y, bvj, acc[1][j]);
          acc[2][j] = fmaf(av.z, bvj, acc[2][j]);
          acc[3][j] = fmaf(av.w, bvj, acc[3][j]);
        }
      }
    }
    __syncthreads();
  }
  int s = n0 >> 7;
#pragma unroll
  for (int i = 0; i < 4; i++) {
    int o = o0 + to * 4 + i;
    float gg = g[o], bb = cb[o], bo = bt[o];
    float m = 0.0f;
#pragma unroll
    for (int j = 0; j < 4; j++) {
      int n = n0 + tn * 4 + j;
      int p = n & 127;
      if (p < 126) {
        float v = fmaf(gg, acc[i][j] + bb, bo);
        v = v > 0.0f ? v : 0.0f;
        m = v > m ? v : m;
      }
    }
    atomicMax((int*)&spfd[((size_t)b * 128 + o) * NSTK + s], __float_as_int(m));
  }
}

// ---------------- K0d: SD[b][s][u] ----------------
__global__ __launch_bounds__(256) void k_sd(const float* __restrict__ sf, float* __restrict__ SD) {
  int b = blockIdx.x, t = threadIdx.x;
  __shared__ float X[32][132];
  for (int idx = t; idx < 128 * 32; idx += 256) {
    int c = idx >> 5, s = idx & 31;
    X[s][c] = sf[((size_t)b * 128 + c) * NSTK + s];
  }
  __syncthreads();
#pragma unroll
  for (int rep = 0; rep < 4; rep++) {
    int p = t + rep * 256;
    int s = p >> 5, u = p & 31;
    float acc = 0.0f;
    for (int c = 0; c < 128; c++) {
      float d = X[s][c] - X[u][c];
      acc = fmaf(d, d, acc);
    }
    SD[(size_t)b * 1024 + p] = acc;
  }
}

// ---------------- K2: FPS + out2 gather ----------------
__global__ __launch_bounds__(128) void k_fps(const float* __restrict__ coor, int* __restrict__ fpsidx,
                                             float* __restrict__ out2) {
  int b = blockIdx.x, t = threadIdx.x;
  __shared__ float X[32][132];
  __shared__ float dist[32];
  __shared__ int far_s;
  __shared__ int sel[16];
  for (int idx = t; idx < 32 * 32; idx += 128) {
    int r = idx >> 5, q = idx & 31;
    *(float4*)&X[r][q * 4] = *(const float4*)&coor[((size_t)b * 32 + r) * 128 + q * 4];
  }
  if (t < 32) dist[t] = 1e10f;
  if (t == 0) far_s = 0;
  __syncthreads();
  for (int it = 0; it < 16; it++) {
    int far = far_s;
    if (t == 0) sel[it] = far;
    if (t < 32) {
      float d = 0.0f;
      for (int c = 0; c < 128; c++) { float dd = X[t][c] - X[far][c]; d = fmaf(dd, dd, d); }
      float dm = dist[t];
      dist[t] = d < dm ? d : dm;
    }
    __syncthreads();
    if (t == 0) {
      float best = -1.0f; int bi = 0;
      for (int m = 0; m < 32; m++) if (dist[m] > best) { best = dist[m]; bi = m; }
      far_s = bi;
    }
    __syncthreads();
  }
  if (t < 16) fpsidx[b * 16 + t] = sel[t];
  __syncthreads();
  for (int idx = t; idx < 16 * 32; idx += 128) {
    int j = idx >> 5, q = idx & 31;
    *(float4*)&out2[((size_t)b * 16 + j) * 128 + q * 4] = *(const float4*)&X[sel[j]][q * 4];
  }
}

// ---------------- K3a: sparse graph ----------------
__global__ __launch_bounds__(256) void k_sparse_graph(const float* __restrict__ sf, const float* __restrict__ spfd,
    float* __restrict__ xs, int* __restrict__ idxs) {
  int b = blockIdx.x, t = threadIdx.x;
  __shared__ float X[32][260];
  __shared__ float sq[32];
  __shared__ float D[32][33];
  for (int idx = t; idx < 32 * 256; idx += 256) {
    int n = idx >> 8, c = idx & 255;
    float v = (c < 128) ? sf[((size_t)b * 128 + c) * NSTK + n]
                        : spfd[((size_t)b * 128 + (c - 128)) * NSTK + n];
    X[n][c] = v;
  }
  __syncthreads();
  for (int idx = t; idx < 32 * 64; idx += 256) {
    int n = idx >> 6, q = idx & 63;
    *(float4*)&xs[((size_t)b * 32 + n) * 256 + q * 4] = *(const float4*)&X[n][q * 4];
  }
  if (t < 32) {
    float s = 0.0f;
    for (int c = 0; c < 256; c++) s = fmaf(X[t][c], X[t][c], s);
    sq[t] = s;
  }
  __syncthreads();
  {
    int n = t >> 3;
    for (int mg = 0; mg < 4; mg++) {
      int m = (t & 7) + mg * 8;
      float dot = 0.0f;
      for (int c = 0; c < 256; c++) dot = fmaf(X[n][c], X[m][c], dot);
      D[n][m] = (sq[n] - 2.0f * dot) + sq[m];
    }
  }
  __syncthreads();
  if (t < 32) {
    float d0 = 1e30f, d1 = 1e30f; int i0 = 0, i1 = 0;
    for (int m = 0; m < 32; m++) {
      float d = D[t][m];
      if (d < d0) { d1 = d0; i1 = i0; d0 = d; i0 = m; }
      else if (d < d1) { d1 = d; i1 = m; }
    }
    idxs[(b * 32 + t) * 2 + 0] = i0;
    idxs[(b * 32 + t) * 2 + 1] = i1;
  }
}

// ---------------- K3b: sparse P/Q ----------------
__global__ __launch_bounds__(256) void k_sparse_pq(const float* __restrict__ xs, const float* __restrict__ W,
    float* __restrict__ Ps, float* __restrict__ Qs) {
  int b = blockIdx.x >> 5, n = blockIdx.x & 31;
  int o = threadIdx.x;
  const float* xr = &xs[((size_t)b * 32 + n) * 256];
  float accP = 0.0f, accQ = 0.0f;
  for (int c = 0; c < 256; c++) {
    float xc = xr[c];
    float w1 = W[(size_t)c * 256 + o];
    float w2 = W[(size_t)(c + 256) * 256 + o];
    accP = fmaf(xc, w1 - w2, accP);
    accQ = fmaf(xc, w2, accQ);
  }
  Ps[((size_t)b * 32 + n) * 256 + o] = accP;
  Qs[((size_t)b * 32 + n) * 256 + o] = accQ;
}

// ---------------- K3c: combine+gather fused ----------------
__global__ __launch_bounds__(256) void k_sparse_cg(const float* __restrict__ Ps, const float* __restrict__ Qs,
    const int* __restrict__ idxs, const int* __restrict__ fps,
    const float* __restrict__ g, const float* __restrict__ cb, const float* __restrict__ bt,
    float* __restrict__ out0) {
  int b = blockIdx.x, j = blockIdx.y, o = threadIdx.x;
  int n = fps[b * 16 + j];
  int i0 = idxs[(b * 32 + n) * 2 + 0], i1 = idxs[(b * 32 + n) * 2 + 1];
  float p = Ps[((size_t)b * 32 + n) * 256 + o];
  float q0 = Qs[((size_t)b * 32 + i0) * 256 + o];
  float q1 = Qs[((size_t)b * 32 + i1) * 256 + o];
  float gg = g[o], bb = cb[o], bo = bt[o];
  float h0 = fmaf(gg, p + q0 + bb, bo); h0 = h0 > 0.0f ? h0 : 0.0f;
  float h1 = fmaf(gg, p + q1 + bb, bo); h1 = h1 > 0.0f ? h1 : 0.0f;
  out0[((size_t)b * 256 + o) * 16 + j] = h0 > h1 ? h0 : h1;
}

// ---------------- K4: dense kNN — FPS rows only x column QUARTERS, compact output --------
// grid (4, 32, 4): m-quarter(8 u-tiles), compact rowblock(64 rows = 4 waves x 16), b.
// 512 blocks = 2 blocks/CU (R15's 256-block/1-per-CU exposed all latency: same 250us at
// half the work). Per-block work = R15's half; latency-hiding regime = R14's.
#define STAGE(p_) { \
  float4 gh[4], gl[4]; \
  _Pragma("unroll") \
  for (int j = 0; j < 4; j++) { \
    size_t gp = (bofs + (size_t)(m0 + j * 32 + sm0)) * 256 + (p_) * 64 + sk8 * 8; \
    gh[j] = *(const float4*)&XH[gp]; gl[j] = *(const float4*)&XL[gp]; } \
  _Pragma("unroll") \
  for (int j = 0; j < 4; j++) { \
    int lo = (j * 32 + sm0) * 72 + sk8 * 8; \
    *(float4*)&BshH[lo] = gh[j]; *(float4*)&BshL[lo] = gl[j]; } }

__global__ __launch_bounds__(256, 2) void k_knn_mfma(const _Float16* __restrict__ XH,
    const _Float16* __restrict__ XL, const float* __restrict__ sqd, const float* __restrict__ SD,
    const int* __restrict__ fps, float* __restrict__ pd, int* __restrict__ pi) {
  const int h = blockIdx.x, rb = blockIdx.y, b = blockIdx.z;
  const int t = threadIdx.x;
  const int w = t >> 6, L = t & 63;
  const int c15 = L & 15, q = L >> 4;
  const int jst = rb >> 1;
  const int ph = (rb & 1) * 64;
  const int s_stk = fps[b * 16 + jst];
  const int nsrc = s_stk * 128 + ph + w * 16;   // source rows for this wave
  const int rc0 = rb * 64 + w * 16;             // compact output row base
  const size_t bofs = (size_t)b * NPNT;

  __shared__ _Float16 BshH[128 * 72];
  __shared__ _Float16 BshL[128 * 72];
  __shared__ float Dw[4][16][132];
  __shared__ float tauW[4][16][4];

  const int sm0 = t >> 3;
  const int sk8 = t & 7;

  half8 ah[4], al[4];
  {
    const _Float16* ap  = XH + (bofs + nsrc + c15) * 256 + q * 8;
    const _Float16* apl = XL + (bofs + nsrc + c15) * 256 + q * 8;
#pragma unroll
    for (int ch = 0; ch < 4; ch++) {
      ah[ch] = *(const half8*)(ap + ch * 32);
      al[ch] = *(const half8*)(apl + ch * 32);
    }
  }
  float snr[4];
#pragma unroll
  for (int r = 0; r < 4; r++) snr[r] = sqd[bofs + nsrc + q * 4 + r];

  float ld[10]; int li[10];
#pragma unroll
  for (int j = 0; j < 10; j++) { ld[j] = 1e30f; li[j] = 0x7fffffff; }

  const bool own_here = ((s_stk >> 3) == h);
  const int r_sel = L >> 2, sl = L & 3;
  float tauR = 1e30f;

  int u = own_here ? s_stk : (h * 8);
  int m0 = u * 128;

#pragma unroll 1
  for (int it = 0; it < 8; it++) {
    int u_next = (it == 0) ? (h * 8 + (own_here ? 0 : 1)) : (u + 1);
    if (own_here && u_next == s_stk) u_next++;

    const float SDv = SD[((size_t)b * 32 + s_stk) * 32 + u];
    float smv[8];
#pragma unroll
    for (int cg = 0; cg < 8; cg++) smv[cg] = sqd[bofs + m0 + cg * 16 + c15];

    f32x4 zz = {0.0f, 0.0f, 0.0f, 0.0f};
    f32x4 acc[8];
#pragma unroll
    for (int cg = 0; cg < 8; cg++) acc[cg] = zz;

    __syncthreads();
    STAGE(0);
    __syncthreads();
#pragma unroll
    for (int chl = 0; chl < 2; chl++) {
#pragma unroll
      for (int cg = 0; cg < 8; cg++) {
        int lo = (cg * 16 + c15) * 72 + chl * 32 + q * 8;
        half8 bh = *(const half8*)&BshH[lo];
        half8 bl = *(const half8*)&BshL[lo];
        acc[cg] = __builtin_amdgcn_mfma_f32_16x16x32_f16(ah[chl], bh, acc[cg], 0, 0, 0);
        acc[cg] = __builtin_amdgcn_mfma_f32_16x16x32_f16(ah[chl], bl, acc[cg], 0, 0, 0);
        acc[cg] = __builtin_amdgcn_mfma_f32_16x16x32_f16(al[chl], bh, acc[cg], 0, 0, 0);
      }
    }
    __syncthreads();
    STAGE(1);
    __syncthreads();
#pragma unroll
    for (int chl = 0; chl < 2; chl++) {
#pragma unroll
      for (int cg = 0; cg < 8; cg++) {
        int lo = (cg * 16 + c15) * 72 + chl * 32 + q * 8;
        half8 bh = *(const half8*)&BshH[lo];
        half8 bl = *(const half8*)&BshL[lo];
        acc[cg] = __builtin_amdgcn_mfma_f32_16x16x32_f16(ah[2 + chl], bh, acc[cg], 0, 0, 0);
        acc[cg] = __builtin_amdgcn_mfma_f32_16x16x32_f16(ah[2 + chl], bl, acc[cg], 0, 0, 0);
        acc[cg] = __builtin_amdgcn_mfma_f32_16x16x32_f16(al[2 + chl], bh, acc[cg], 0, 0, 0);
      }
    }

#pragma unroll
    for (int cg = 0; cg < 8; cg++) {
      float basec = SDv + smv[cg];
#pragma unroll
      for (int r = 0; r < 4; r++)
        Dw[w][q * 4 + r][cg * 16 + c15] = snr[r] + basec - 2.0f * acc[cg][r];
    }
    if (it == 0) {
#pragma unroll
      for (int jj = 0; jj < 8; jj++) {
        float4 dv = *(const float4*)&Dw[w][r_sel][jj * 16 + sl * 4];
        int ib = m0 + jj * 16 + sl * 4;
        insert10(ld, li, dv.x, ib + 0);
        insert10(ld, li, dv.y, ib + 1);
        insert10(ld, li, dv.z, ib + 2);
        insert10(ld, li, dv.w, ib + 3);
      }
    } else {
      bool any = false;
#pragma unroll
      for (int jj = 0; jj < 8; jj++) {
        float4 dv = *(const float4*)&Dw[w][r_sel][jj * 16 + sl * 4];
        any = any || (dv.x <= tauR) || (dv.y <= tauR) || (dv.z <= tauR) || (dv.w <= tauR);
      }
      if (any) {
#pragma unroll
        for (int jj = 0; jj < 8; jj++) {
          float4 dv = *(const float4*)&Dw[w][r_sel][jj * 16 + sl * 4];
          int ib = m0 + jj * 16 + sl * 4;
          if (dv.x <= tauR) insert10(ld, li, dv.x, ib + 0);
          if (dv.y <= tauR) insert10(ld, li, dv.y, ib + 1);
          if (dv.z <= tauR) insert10(ld, li, dv.z, ib + 2);
          if (dv.w <= tauR) insert10(ld, li, dv.w, ib + 3);
        }
      }
    }
    tauW[w][r_sel][sl] = ld[9];
    float4 tv = *(const float4*)&tauW[w][r_sel][0];
    tauR = fminf(fminf(tv.x, tv.y), fminf(tv.z, tv.w));

    u = u_next; m0 = u_next * 128;
  }

#pragma unroll
  for (int j = 0; j < 10; j++) {
    Dw[w][r_sel][sl * 10 + j] = ld[j];
    Dw[w][r_sel][40 + sl * 10 + j] = __int_as_float(li[j]);
  }
  if (L < 16) {
    float fd[10]; int fi[10];
#pragma unroll
    for (int j = 0; j < 10; j++) { fd[j] = 1e30f; fi[j] = 0x7fffffff; }
    for (int x = 0; x < 40; x++)
      insert10(fd, fi, Dw[w][L][x], __float_as_int(Dw[w][L][40 + x]));
    size_t row = (size_t)b * 2048 + rc0 + L;   // compact row
#pragma unroll
    for (int j = 0; j < 10; j++) {
      pd[(row * 4 + h) * 10 + j] = fd[j];
      pi[(row * 4 + h) * 10 + j] = fi[j];
    }
  }
}

// ---------------- K4b: merge the 4 quarter-lists (compact rows) ----------------
__global__ __launch_bounds__(256) void k_knn_merge(const float* __restrict__ pd, const int* __restrict__ pi,
                                                   int* __restrict__ knnc) {
  size_t row = blockIdx.x * 256 + threadIdx.x;   // 32 blocks: 8192 compact rows
  float ld[10]; int li[10];
#pragma unroll
  for (int jj = 0; jj < 10; jj++) { ld[jj] = pd[row * 40 + jj]; li[jj] = pi[row * 40 + jj]; }
#pragma unroll
  for (int jj = 10; jj < 40; jj++) insert10(ld, li, pd[row * 40 + jj], pi[row * 40 + jj]);
#pragma unroll
  for (int jj = 0; jj < 10; jj++) knnc[row * 10 + jj] = li[jj];
}

// ---------------- K5: Q' = g*Q for all rows; P' = g*(P+cb)+bt only for FPS rows ----------
__global__ __launch_bounds__(256, 2) void k_pq_mfma(const _Float16* __restrict__ XH, const _Float16* __restrict__ XL,
    const _Float16* __restrict__ WPh, const _Float16* __restrict__ WPl,
    const _Float16* __restrict__ WQh, const _Float16* __restrict__ WQl,
    const int* __restrict__ fps, const float* __restrict__ g, const float* __restrict__ cb,
    const float* __restrict__ bt, float* __restrict__ Pc, float* __restrict__ Qp) {
  const int b = blockIdx.z;
  const int t = threadIdx.x, w = t >> 6, L = t & 63;
  const int c15 = L & 15, q = L >> 4;
  const int ow = blockIdx.y * 128 + (w >> 1) * 64;
  const size_t bofs = (size_t)b * NPNT;
  f32x4 zz = {0.0f, 0.0f, 0.0f, 0.0f};

  {
    const int nw = blockIdx.x * 32 + (w & 1) * 16;
    f32x4 accQ[4];
#pragma unroll
    for (int cg = 0; cg < 4; cg++) accQ[cg] = zz;
    const _Float16* ap  = XH + (bofs + nw + c15) * 256 + q * 8;
    const _Float16* apl = XL + (bofs + nw + c15) * 256 + q * 8;
#pragma unroll
    for (int ch = 0; ch < 8; ch++) {
      half8 a_h = *(const half8*)(ap + ch * 32);
      half8 a_l = *(const half8*)(apl + ch * 32);
#pragma unroll
      for (int cg = 0; cg < 4; cg++) {
        size_t wb = (size_t)(ow + cg * 16 + c15) * 256 + ch * 32 + q * 8;
        half8 bqh = *(const half8*)(WQh + wb);
        half8 bql = *(const half8*)(WQl + wb);
        accQ[cg] = __builtin_amdgcn_mfma_f32_16x16x32_f16(a_h, bqh, accQ[cg], 0, 0, 0);
        accQ[cg] = __builtin_amdgcn_mfma_f32_16x16x32_f16(a_h, bql, accQ[cg], 0, 0, 0);
        accQ[cg] = __builtin_amdgcn_mfma_f32_16x16x32_f16(a_l, bqh, accQ[cg], 0, 0, 0);
      }
    }
#pragma unroll
    for (int cg = 0; cg < 4; cg++) {
      int o = ow + cg * 16 + c15;
      float gg = g[o];
#pragma unroll
      for (int r = 0; r < 4; r++) {
        Qp[(bofs + nw + q * 4 + r) * 256 + o] = gg * accQ[cg][r];
      }
    }
  }

  if (blockIdx.x < 64) {
    const int m0 = blockIdx.x * 32 + (w & 1) * 16;
    const int jst = m0 >> 7;
    const int pbase = m0 & 127;
    const int nsrc = fps[b * 16 + jst] * 128 + pbase;
    f32x4 accP[4];
#pragma unroll
    for (int cg = 0; cg < 4; cg++) accP[cg] = zz;
    const _Float16* ap  = XH + (bofs + nsrc + c15) * 256 + q * 8;
    const _Float16* apl = XL + (bofs + nsrc + c15) * 256 + q * 8;
#pragma unroll
    for (int ch = 0; ch < 8; ch++) {
      half8 a_h = *(const half8*)(ap + ch * 32);
      half8 a_l = *(const half8*)(apl + ch * 32);
#pragma unroll
      for (int cg = 0; cg < 4; cg++) {
        size_t wb = (size_t)(ow + cg * 16 + c15) * 256 + ch * 32 + q * 8;
        half8 bph = *(const half8*)(WPh + wb);
        half8 bpl = *(const half8*)(WPl + wb);
        accP[cg] = __builtin_amdgcn_mfma_f32_16x16x32_f16(a_h, bph, accP[cg], 0, 0, 0);
        accP[cg] = __builtin_amdgcn_mfma_f32_16x16x32_f16(a_h, bpl, accP[cg], 0, 0, 0);
        accP[cg] = __builtin_amdgcn_mfma_f32_16x16x32_f16(a_l, bph, accP[cg], 0, 0, 0);
      }
    }
#pragma unroll
    for (int cg = 0; cg < 4; cg++) {
      int o = ow + cg * 16 + c15;
      float gg = g[o], bb = cb[o], bo = bt[o];
#pragma unroll
      for (int r = 0; r < 4; r++) {
        Pc[(((size_t)b * 16 + jst) * 128 + pbase + q * 4 + r) * 256 + o] =
            fmaf(gg, accP[cg][r] + bb, bo);
      }
    }
  }
}

// ---------------- K6: build im2col E from compact P'/knnc + Q' ----------------
__global__ __launch_bounds__(256) void k_build_E(const float* __restrict__ Pc, const float* __restrict__ Qp,
    const int* __restrict__ knnc, float* __restrict__ E) {
  int pp = blockIdx.x, j = blockIdx.y, b = blockIdx.z;
  int t = threadIdx.x;
  float v[3];
#pragma unroll
  for (int dp = 0; dp < 3; dp++) {
    int p = 2 * pp - 1 + dp;
    float val = 0.0f;
    if (p >= 0 && p < 128) {
      size_t m = ((size_t)b * 16 + j) * 128 + p;
      float pv = Pc[m * 256 + t];
      const int* id = &knnc[m * 10];
      float mx = 0.0f;
#pragma unroll
      for (int k = 0; k < 10; k++) {
        float qv = Qp[((size_t)b * NPNT + id[k]) * 256 + t];
        float h = pv + qv;
        mx = h > mx ? h : mx;
      }
      val = mx;
    }
    v[dp] = val;
  }
  size_t base = ((size_t)(b * 16 + j) * 64 + pp) * 768;
  E[base + 3 * t + 0] = v[0];
  E[base + 3 * t + 1] = v[1];
  E[base + 3 * t + 2] = v[2];
}

// ---------------- K7: downsample GEMM ----------------
__global__ __launch_bounds__(256) void k_ds_gemm(const float* __restrict__ Wd, const float* __restrict__ E,
    const float* __restrict__ cb, const float* __restrict__ g, const float* __restrict__ bt,
    float* __restrict__ out1) {
  int j0 = blockIdx.x * 64, o0 = blockIdx.y * 64, b = blockIdx.z;
  int t = threadIdx.x;
  __shared__ float A[32][68];
  __shared__ float Bs[32][68];
  float acc[4][4];
#pragma unroll
  for (int i = 0; i < 4; i++)
#pragma unroll
    for (int j = 0; j < 4; j++) acc[i][j] = 0.0f;
  int tj = t & 15, to = t >> 4;
  for (int kc = 0; kc < 768; kc += 32) {
    {
      int ol = t >> 2, q = t & 3;
      const float* src = &Wd[(size_t)(o0 + ol) * 768 + kc + q * 8];
      float4 v0 = *(const float4*)src, v1 = *(const float4*)(src + 4);
      int cc = q * 8;
      A[cc+0][ol] = v0.x; A[cc+1][ol] = v0.y; A[cc+2][ol] = v0.z; A[cc+3][ol] = v0.w;
      A[cc+4][ol] = v1.x; A[cc+5][ol] = v1.y; A[cc+6][ol] = v1.z; A[cc+7][ol] = v1.w;
    }
    {
      int jl = t >> 2, q = t & 3;
      const float* src = &E[((size_t)b * 1024 + j0 + jl) * 768 + kc + q * 8];
      float4 v0 = *(const float4*)src, v1 = *(const float4*)(src + 4);
      int cc = q * 8;
      Bs[cc+0][jl] = v0.x; Bs[cc+1][jl] = v0.y; Bs[cc+2][jl] = v0.z; Bs[cc+3][jl] = v0.w;
      Bs[cc+4][jl] = v1.x; Bs[cc+5][jl] = v1.y; Bs[cc+6][jl] = v1.z; Bs[cc+7][jl] = v1.w;
    }
    __syncthreads();
#pragma unroll 4
    for (int k = 0; k < 32; k++) {
      float4 a = *(const float4*)&A[k][to * 4];
      float4 bv = *(const float4*)&Bs[k][tj * 4];
      float av[4] = {a.x, a.y, a.z, a.w};
      float bb[4] = {bv.x, bv.y, bv.z, bv.w};
#pragma unroll
      for (int i = 0; i < 4; i++)
#pragma unroll
        for (int j = 0; j < 4; j++)
          acc[i][j] = fmaf(av[i], bb[j], acc[i][j]);
    }
    __syncthreads();
  }
#pragma unroll
  for (int i = 0; i < 4; i++) {
    int o = o0 + to * 4 + i;
    float gg = g[o], bb = cb[o], bo = bt[o];
    float4 v;
    float x0 = fmaf(gg, acc[i][0] + bb, bo); v.x = x0 > 0.0f ? x0 : 0.0f;
    float x1 = fmaf(gg, acc[i][1] + bb, bo); v.y = x1 > 0.0f ? x1 : 0.0f;
    float x2 = fmaf(gg, acc[i][2] + bb, bo); v.z = x2 > 0.0f ? x2 : 0.0f;
    float x3 = fmaf(gg, acc[i][3] + bb, bo); v.w = x3 > 0.0f ? x3 : 0.0f;
    *(float4*)&out1[((size_t)b * 256 + o) * 1024 + j0 + tj * 4] = v;
  }
}

extern "C" void kernel_launch(void* const* d_in, const int* in_sizes, int n_in,
                              void* d_out, int out_size, void* d_ws, size_t ws_size,
                              hipStream_t stream) {
  (void)in_sizes; (void)n_in; (void)out_size; (void)ws_size;
  const float* sf    = (const float*)d_in[0];
  const float* df    = (const float*)d_in[1];
  const float* coor  = (const float*)d_in[2];
  const float* d2sw  = (const float*)d_in[3];
  const float* d2sb  = (const float*)d_in[4];
  const float* d2sg  = (const float*)d_in[5];
  const float* d2sbt = (const float*)d_in[6];
  const float* spW   = (const float*)d_in[7];
  const float* spb   = (const float*)d_in[8];
  const float* spg   = (const float*)d_in[9];
  const float* spbt  = (const float*)d_in[10];
  const float* dnW   = (const float*)d_in[11];
  const float* dnb   = (const float*)d_in[12];
  const float* dng   = (const float*)d_in[13];
  const float* dnbt  = (const float*)d_in[14];
  const float* dsw   = (const float*)d_in[15];
  const float* dsb   = (const float*)d_in[16];
  const float* dsg   = (const float*)d_in[17];
  const float* dsbt  = (const float*)d_in[18];

  float* ws   = (float*)d_ws;
  float* Pc   = ws + OFF_P;
  float* Qp   = ws + OFF_Q;
  float* SQD  = ws + OFF_SQD;
  float* SPFD = ws + OFF_SPFD;
  float* XS   = ws + OFF_XS;
  float* PS   = ws + OFF_PS;
  float* QS   = ws + OFF_QS;
  int*   KNNC = (int*)(ws + OFF_KNN);
  int*   IDXS = (int*)(ws + OFF_IDXS);
  int*   FPS  = (int*)(ws + OFF_FPS);
  float* SD   = ws + OFF_SD;
  _Float16* XT2H = (_Float16*)(ws + OFF_XT);
  _Float16* XT2L = XT2H + (size_t)4 * NPNT * 256;
  float* E = ws + OFF_XT;
  _Float16* WPh = (_Float16*)(ws + OFF_WSP);
  _Float16* WPl = WPh + 65536;
  _Float16* WQh = WPh + 131072;
  _Float16* WQl = WPh + 196608;
  // compact quarter-lists alias the Q region (consumed before k_pq_mfma writes Q')
  float* PDL = ws + OFF_Q;
  int*   PIL = (int*)(ws + OFF_Q + 327680);

  float* out0 = (float*)d_out;
  float* out1 = out0 + 16384;
  float* out2 = out1 + 1048576;

  hipMemsetAsync(SPFD, 0, 16384 * sizeof(float), stream);

  k_split256<<<dim3(4, 64), 256, 0, stream>>>(df, sf, XT2H, XT2L, SQD);
  k_splitW<<<dim3(256), 256, 0, stream>>>(dnW, WPh, WPl, WQh, WQl);
  k_d2s<<<dim3(4, 2, 64), 256, 0, stream>>>(df, d2sw, d2sb, d2sg, d2sbt, SPFD);
  k_sd<<<dim3(4), 256, 0, stream>>>(sf, SD);
  k_fps<<<dim3(4), 128, 0, stream>>>(coor, FPS, out2);
  k_sparse_graph<<<dim3(4), 256, 0, stream>>>(sf, SPFD, XS, IDXS);
  k_sparse_pq<<<dim3(128), 256, 0, stream>>>(XS, spW, PS, QS);
  k_sparse_cg<<<dim3(4, 16), 256, 0, stream>>>(PS, QS, IDXS, FPS, spg, spb, spbt, out0);
  k_knn_mfma<<<dim3(4, 32, 4), 256, 0, stream>>>(XT2H, XT2L, SQD, SD, FPS, PDL, PIL);
  k_knn_merge<<<dim3(32), 256, 0, stream>>>(PDL, PIL, KNNC);
  k_pq_mfma<<<dim3(128, 2, 4), 256, 0, stream>>>(XT2H, XT2L, WPh, WPl, WQh, WQl,
                                                 FPS, dng, dnb, dnbt, Pc, Qp);
  k_build_E<<<dim3(64, 16, 4), 256, 0, stream>>>(Pc, Qp, KNNC, E);
  k_ds_gemm<<<dim3(16, 4, 4), 256, 0, stream>>>(dsw, E, dsb, dsg, dsbt, out1);
}

// Round 17
// 509.586 us; speedup vs baseline: 1.1985x; 1.0308x over previous
//
#include <hip/hip_runtime.h>

#define NPNT 4096
#define NSTK 32

typedef _Float16 half8 __attribute__((ext_vector_type(8)));
typedef float f32x4 __attribute__((ext_vector_type(4)));

// ---------------- workspace layout (floats) ----------------
static const size_t OFF_XT   = 0;          // XT2H/XT2L (f16) live here; E aliases later
static const size_t OFF_P    = 4194304;    // P' compact fp32 [b,16,128,256] = 2097152
static const size_t OFF_Q    = 8388608;    // Q' fp32 [b,n,256]; PDL/PIL alias before k_pq
static const size_t OFF_SQD  = 12582912;   // 16384
static const size_t OFF_SPFD = 12599296;   // 16384
static const size_t OFF_XS   = 12615680;   // 32768
static const size_t OFF_PS   = 12648448;   // 32768
static const size_t OFF_QS   = 12681216;   // 32768
static const size_t OFF_WSP  = 12746752;   // W f16 splits
static const size_t OFF_KNN  = 13402112;   // knnc compact 81920 (int)
static const size_t OFF_IDXS = 13565952;   // 256 (int)
static const size_t OFF_FPS  = 13566208;   // 64 (int)
static const size_t OFF_SD   = 13566272;   // 4096

__device__ __forceinline__ bool lexlt(float d1, int i1, float d2, int i2) {
  return (d1 < d2) || (d1 == d2 && i1 < i2);
}
__device__ __forceinline__ void insert10(float ld[10], int li[10], float d, int i) {
  if (!lexlt(d, i, ld[9], li[9])) return;
  ld[9] = d; li[9] = i;
#pragma unroll
  for (int j = 9; j > 0; j--) {
    if (lexlt(ld[j], li[j], ld[j-1], li[j-1])) {
      float td = ld[j]; ld[j] = ld[j-1]; ld[j-1] = td;
      int ti = li[j]; li[j] = li[j-1]; li[j-1] = ti;
    }
  }
}

// ---------------- K0e: fused transpose+broadcast+split+sqd ----------
__global__ __launch_bounds__(256) void k_split256(const float* __restrict__ df, const float* __restrict__ sf,
    _Float16* __restrict__ XH, _Float16* __restrict__ XL, float* __restrict__ sqd) {
  int b = blockIdx.x, n0 = blockIdx.y * 64;
  int t = threadIdx.x;
  int s0 = n0 >> 7;
  __shared__ float T[128][68];
  __shared__ _Float16 Sh[128], Sl[128];
  {
    int c = t >> 1, nh = (t & 1) * 32;
    const float* src = &df[((size_t)b * 128 + c) * NPNT + n0 + nh];
#pragma unroll
    for (int j = 0; j < 8; j++) *(float4*)&T[c][nh + j * 4] = *(const float4*)&src[j * 4];
  }
  if (t < 128) {
    float x = sf[((size_t)b * 128 + t) * NSTK + s0];
    _Float16 hi = (_Float16)x;
    Sh[t] = hi; Sl[t] = (_Float16)(x - (float)hi);
  }
  __syncthreads();
  {
    int n = t >> 2, cseg = (t & 3) * 32;
    size_t base = ((size_t)b * NPNT + n0 + n) * 256;
    float s = 0.0f;
#pragma unroll
    for (int k = 0; k < 4; k++) {
      half8 hv, lv, shv, slv;
#pragma unroll
      for (int e = 0; e < 8; e++) {
        float x = T[cseg + k * 8 + e][n];
        s = fmaf(x, x, s);
        _Float16 hi = (_Float16)x;
        hv[e] = hi; lv[e] = (_Float16)(x - (float)hi);
        shv[e] = Sh[cseg + k * 8 + e];
        slv[e] = Sl[cseg + k * 8 + e];
      }
      *(half8*)&XH[base + cseg + k * 8] = hv;
      *(half8*)&XL[base + cseg + k * 8] = lv;
      *(half8*)&XH[base + 128 + cseg + k * 8] = shv;
      *(half8*)&XL[base + 128 + cseg + k * 8] = slv;
    }
    s += __shfl_xor(s, 1);
    s += __shfl_xor(s, 2);
    if ((t & 3) == 0) sqd[(size_t)b * NPNT + n0 + n] = s;
  }
}

// ---------------- K0f: W split ----------------
__global__ __launch_bounds__(256) void k_splitW(const float* __restrict__ W,
    _Float16* __restrict__ WPh, _Float16* __restrict__ WPl,
    _Float16* __restrict__ WQh, _Float16* __restrict__ WQl) {
  int k = blockIdx.x, o = threadIdx.x;
  float w1 = W[(size_t)k * 256 + o];
  float w2 = W[(size_t)(k + 256) * 256 + o];
  float p = w1 - w2;
  _Float16 ph = (_Float16)p;  WPh[(size_t)o * 256 + k] = ph;
  WPl[(size_t)o * 256 + k] = (_Float16)(p - (float)ph);
  _Float16 qh = (_Float16)w2; WQh[(size_t)o * 256 + k] = qh;
  WQl[(size_t)o * 256 + k] = (_Float16)(w2 - (float)qh);
}

// ---------------- K1: DenseToSparse conv(1,3)+BN+ReLU+max — full-stroke blocks -----------
// grid (4, 2, 32): b, o-half(64), stroke. Max over all 126 valid points computed
// in-register -> direct store (no atomicMax, no memset pre-pass).
__global__ __launch_bounds__(256) void k_d2s(const float* __restrict__ df, const float* __restrict__ w,
    const float* __restrict__ cb, const float* __restrict__ g, const float* __restrict__ bt,
    float* __restrict__ spfd) {
  int b = blockIdx.x, o0 = blockIdx.y * 64, s = blockIdx.z;
  int n0 = s * 128;
  int t = threadIdx.x;
  __shared__ float A[96][64];    // [iloc*3+kw][o]
  __shared__ float Bs[32][132];  // [iloc][128 pts + halo]
  float acc[4][8];
#pragma unroll
  for (int i = 0; i < 4; i++)
#pragma unroll
    for (int j = 0; j < 8; j++) acc[i][j] = 0.0f;
  int tn = t & 15, to = t >> 4;   // tn: 8-point group, to: o-quad
  for (int ic = 0; ic < 128; ic += 32) {
    {
      int ol = t >> 2, q = t & 3;
      const float* src = &w[((size_t)(o0 + ol) * 128 + ic) * 3 + q * 24];
#pragma unroll
      for (int r = 0; r < 6; r++) {
        float4 v = *(const float4*)&src[r * 4];
        int e = q * 24 + r * 4;
        A[e+0][ol] = v.x; A[e+1][ol] = v.y; A[e+2][ol] = v.z; A[e+3][ol] = v.w;
      }
    }
    for (int idx = t; idx < 32 * 33; idx += 256) {
      int row = idx / 33, f4 = idx % 33;
      int nb = n0 + f4 * 4;
      const float* srow = &df[((size_t)b * 128 + ic + row) * NPNT];
      float4 v;
      if (nb + 3 < NPNT) v = *(const float4*)&srow[nb];
      else {
        v.x = srow[nb   < NPNT ? nb   : NPNT-1];
        v.y = srow[nb+1 < NPNT ? nb+1 : NPNT-1];
        v.z = srow[nb+2 < NPNT ? nb+2 : NPNT-1];
        v.w = srow[nb+3 < NPNT ? nb+3 : NPNT-1];
      }
      *(float4*)&Bs[row][f4 * 4] = v;
    }
    __syncthreads();
#pragma unroll 2
    for (int ii = 0; ii < 32; ii++) {
      float bv[12];
      *(float4*)&bv[0] = *(const float4*)&Bs[ii][tn * 8];
      *(float4*)&bv[4] = *(const float4*)&Bs[ii][tn * 8 + 4];
      *(float4*)&bv[8] = *(const float4*)&Bs[ii][tn * 8 + 8];
#pragma unroll
      for (int kw = 0; kw < 3; kw++) {
        float4 av = *(const float4*)&A[ii * 3 + kw][to * 4];
#pragma unroll
        for (int j = 0; j < 8; j++) {
          float bvj = bv[kw + j];
          acc[0][j] = fmaf(av.x, bvj, acc[0][j]);
          acc[1][j] = fmaf(av.y, bvj, acc[1][j]);
          acc[2][j] = fmaf(av.z, bvj, acc[2][j]);
          acc[3][j] = fmaf(av.w, bvj, acc[3][j]);
        }
      }
    }
    __syncthreads();
  }
  // per-lane max over its 8 points, then 16-lane tree reduce (lanes tn share o-quad to)
  __shared__ float Mx[4][16][16];   // [wave][to(4 per wave)*?]... use flat: [to][tn]
  // simpler: reduce via LDS Dr[64 o][16 tn]
  __shared__ float Dr[64][17];
#pragma unroll
  for (int i = 0; i < 4; i++) {
    int o = o0 + to * 4 + i;
    float gg = g[o], bb = cb[o], bo = bt[o];
    float m = 0.0f;
#pragma unroll
    for (int j = 0; j < 8; j++) {
      int p = tn * 8 + j;
      if (p < 126) {
        float v = fmaf(gg, acc[i][j] + bb, bo);
        v = v > 0.0f ? v : 0.0f;
        m = v > m ? v : m;
      }
    }
    Dr[to * 4 + i][tn] = m;
  }
  __syncthreads();
  if (t < 64) {
    float m = 0.0f;
#pragma unroll
    for (int k = 0; k < 16; k++) m = Dr[t][k] > m ? Dr[t][k] : m;
    spfd[((size_t)b * 128 + o0 + t) * NSTK + s] = m;
  }
  (void)Mx;
}

// ---------------- K2: FPS + out2 gather ----------------
__global__ __launch_bounds__(128) void k_fps(const float* __restrict__ coor, int* __restrict__ fpsidx,
                                             float* __restrict__ out2) {
  int b = blockIdx.x, t = threadIdx.x;
  __shared__ float X[32][132];
  __shared__ float dist[32];
  __shared__ int far_s;
  __shared__ int sel[16];
  for (int idx = t; idx < 32 * 32; idx += 128) {
    int r = idx >> 5, q = idx & 31;
    *(float4*)&X[r][q * 4] = *(const float4*)&coor[((size_t)b * 32 + r) * 128 + q * 4];
  }
  if (t < 32) dist[t] = 1e10f;
  if (t == 0) far_s = 0;
  __syncthreads();
  for (int it = 0; it < 16; it++) {
    int far = far_s;
    if (t == 0) sel[it] = far;
    if (t < 32) {
      float d = 0.0f;
      for (int c = 0; c < 128; c++) { float dd = X[t][c] - X[far][c]; d = fmaf(dd, dd, d); }
      float dm = dist[t];
      dist[t] = d < dm ? d : dm;
    }
    __syncthreads();
    if (t == 0) {
      float best = -1.0f; int bi = 0;
      for (int m = 0; m < 32; m++) if (dist[m] > best) { best = dist[m]; bi = m; }
      far_s = bi;
    }
    __syncthreads();
  }
  if (t < 16) fpsidx[b * 16 + t] = sel[t];
  __syncthreads();
  for (int idx = t; idx < 16 * 32; idx += 128) {
    int j = idx >> 5, q = idx & 31;
    *(float4*)&out2[((size_t)b * 16 + j) * 128 + q * 4] = *(const float4*)&X[sel[j]][q * 4];
  }
}

// ---------------- K3a: sparse graph + SD (k_sd fused: reuses staged X) ----------------
__global__ __launch_bounds__(256) void k_sparse_graph(const float* __restrict__ sf, const float* __restrict__ spfd,
    float* __restrict__ xs, int* __restrict__ idxs, float* __restrict__ SD) {
  int b = blockIdx.x, t = threadIdx.x;
  __shared__ float X[32][260];
  __shared__ float sq[32];
  __shared__ float D[32][33];
  for (int idx = t; idx < 32 * 256; idx += 256) {
    int n = idx >> 8, c = idx & 255;
    float v = (c < 128) ? sf[((size_t)b * 128 + c) * NSTK + n]
                        : spfd[((size_t)b * 128 + (c - 128)) * NSTK + n];
    X[n][c] = v;
  }
  __syncthreads();
  for (int idx = t; idx < 32 * 64; idx += 256) {
    int n = idx >> 6, q = idx & 63;
    *(float4*)&xs[((size_t)b * 32 + n) * 256 + q * 4] = *(const float4*)&X[n][q * 4];
  }
  // SD over the sf half (fused from k_sd)
#pragma unroll
  for (int rep = 0; rep < 4; rep++) {
    int p = t + rep * 256;
    int s = p >> 5, u = p & 31;
    float acc = 0.0f;
    for (int c = 0; c < 128; c++) {
      float d = X[s][c] - X[u][c];
      acc = fmaf(d, d, acc);
    }
    SD[(size_t)b * 1024 + p] = acc;
  }
  if (t < 32) {
    float s = 0.0f;
    for (int c = 0; c < 256; c++) s = fmaf(X[t][c], X[t][c], s);
    sq[t] = s;
  }
  __syncthreads();
  {
    int n = t >> 3;
    for (int mg = 0; mg < 4; mg++) {
      int m = (t & 7) + mg * 8;
      float dot = 0.0f;
      for (int c = 0; c < 256; c++) dot = fmaf(X[n][c], X[m][c], dot);
      D[n][m] = (sq[n] - 2.0f * dot) + sq[m];
    }
  }
  __syncthreads();
  if (t < 32) {
    float d0 = 1e30f, d1 = 1e30f; int i0 = 0, i1 = 0;
    for (int m = 0; m < 32; m++) {
      float d = D[t][m];
      if (d < d0) { d1 = d0; i1 = i0; d0 = d; i0 = m; }
      else if (d < d1) { d1 = d; i1 = m; }
    }
    idxs[(b * 32 + t) * 2 + 0] = i0;
    idxs[(b * 32 + t) * 2 + 1] = i1;
  }
}

// ---------------- K3b: sparse P/Q ----------------
__global__ __launch_bounds__(256) void k_sparse_pq(const float* __restrict__ xs, const float* __restrict__ W,
    float* __restrict__ Ps, float* __restrict__ Qs) {
  int b = blockIdx.x >> 5, n = blockIdx.x & 31;
  int o = threadIdx.x;
  const float* xr = &xs[((size_t)b * 32 + n) * 256];
  float accP = 0.0f, accQ = 0.0f;
  for (int c = 0; c < 256; c++) {
    float xc = xr[c];
    float w1 = W[(size_t)c * 256 + o];
    float w2 = W[(size_t)(c + 256) * 256 + o];
    accP = fmaf(xc, w1 - w2, accP);
    accQ = fmaf(xc, w2, accQ);
  }
  Ps[((size_t)b * 32 + n) * 256 + o] = accP;
  Qs[((size_t)b * 32 + n) * 256 + o] = accQ;
}

// ---------------- K3c: combine+gather fused ----------------
__global__ __launch_bounds__(256) void k_sparse_cg(const float* __restrict__ Ps, const float* __restrict__ Qs,
    const int* __restrict__ idxs, const int* __restrict__ fps,
    const float* __restrict__ g, const float* __restrict__ cb, const float* __restrict__ bt,
    float* __restrict__ out0) {
  int b = blockIdx.x, j = blockIdx.y, o = threadIdx.x;
  int n = fps[b * 16 + j];
  int i0 = idxs[(b * 32 + n) * 2 + 0], i1 = idxs[(b * 32 + n) * 2 + 1];
  float p = Ps[((size_t)b * 32 + n) * 256 + o];
  float q0 = Qs[((size_t)b * 32 + i0) * 256 + o];
  float q1 = Qs[((size_t)b * 32 + i1) * 256 + o];
  float gg = g[o], bb = cb[o], bo = bt[o];
  float h0 = fmaf(gg, p + q0 + bb, bo); h0 = h0 > 0.0f ? h0 : 0.0f;
  float h1 = fmaf(gg, p + q1 + bb, bo); h1 = h1 > 0.0f ? h1 : 0.0f;
  out0[((size_t)b * 256 + o) * 16 + j] = h0 > h1 ? h0 : h1;
}

// ---------------- K4: dense kNN — FPS rows only x column QUARTERS (R16 exact) ------------
#define STAGE(p_) { \
  float4 gh[4], gl[4]; \
  _Pragma("unroll") \
  for (int j = 0; j < 4; j++) { \
    size_t gp = (bofs + (size_t)(m0 + j * 32 + sm0)) * 256 + (p_) * 64 + sk8 * 8; \
    gh[j] = *(const float4*)&XH[gp]; gl[j] = *(const float4*)&XL[gp]; } \
  _Pragma("unroll") \
  for (int j = 0; j < 4; j++) { \
    int lo = (j * 32 + sm0) * 72 + sk8 * 8; \
    *(float4*)&BshH[lo] = gh[j]; *(float4*)&BshL[lo] = gl[j]; } }

__global__ __launch_bounds__(256, 2) void k_knn_mfma(const _Float16* __restrict__ XH,
    const _Float16* __restrict__ XL, const float* __restrict__ sqd, const float* __restrict__ SD,
    const int* __restrict__ fps, float* __restrict__ pd, int* __restrict__ pi) {
  const int h = blockIdx.x, rb = blockIdx.y, b = blockIdx.z;
  const int t = threadIdx.x;
  const int w = t >> 6, L = t & 63;
  const int c15 = L & 15, q = L >> 4;
  const int jst = rb >> 1;
  const int ph = (rb & 1) * 64;
  const int s_stk = fps[b * 16 + jst];
  const int nsrc = s_stk * 128 + ph + w * 16;
  const int rc0 = rb * 64 + w * 16;
  const size_t bofs = (size_t)b * NPNT;

  __shared__ _Float16 BshH[128 * 72];
  __shared__ _Float16 BshL[128 * 72];
  __shared__ float Dw[4][16][132];
  __shared__ float tauW[4][16][4];

  const int sm0 = t >> 3;
  const int sk8 = t & 7;

  half8 ah[4], al[4];
  {
    const _Float16* ap  = XH + (bofs + nsrc + c15) * 256 + q * 8;
    const _Float16* apl = XL + (bofs + nsrc + c15) * 256 + q * 8;
#pragma unroll
    for (int ch = 0; ch < 4; ch++) {
      ah[ch] = *(const half8*)(ap + ch * 32);
      al[ch] = *(const half8*)(apl + ch * 32);
    }
  }
  float snr[4];
#pragma unroll
  for (int r = 0; r < 4; r++) snr[r] = sqd[bofs + nsrc + q * 4 + r];

  float ld[10]; int li[10];
#pragma unroll
  for (int j = 0; j < 10; j++) { ld[j] = 1e30f; li[j] = 0x7fffffff; }

  const bool own_here = ((s_stk >> 3) == h);
  const int r_sel = L >> 2, sl = L & 3;
  float tauR = 1e30f;

  int u = own_here ? s_stk : (h * 8);
  int m0 = u * 128;

#pragma unroll 1
  for (int it = 0; it < 8; it++) {
    int u_next = (it == 0) ? (h * 8 + (own_here ? 0 : 1)) : (u + 1);
    if (own_here && u_next == s_stk) u_next++;

    const float SDv = SD[((size_t)b * 32 + s_stk) * 32 + u];
    float smv[8];
#pragma unroll
    for (int cg = 0; cg < 8; cg++) smv[cg] = sqd[bofs + m0 + cg * 16 + c15];

    f32x4 zz = {0.0f, 0.0f, 0.0f, 0.0f};
    f32x4 acc[8];
#pragma unroll
    for (int cg = 0; cg < 8; cg++) acc[cg] = zz;

    __syncthreads();
    STAGE(0);
    __syncthreads();
#pragma unroll
    for (int chl = 0; chl < 2; chl++) {
#pragma unroll
      for (int cg = 0; cg < 8; cg++) {
        int lo = (cg * 16 + c15) * 72 + chl * 32 + q * 8;
        half8 bh = *(const half8*)&BshH[lo];
        half8 bl = *(const half8*)&BshL[lo];
        acc[cg] = __builtin_amdgcn_mfma_f32_16x16x32_f16(ah[chl], bh, acc[cg], 0, 0, 0);
        acc[cg] = __builtin_amdgcn_mfma_f32_16x16x32_f16(ah[chl], bl, acc[cg], 0, 0, 0);
        acc[cg] = __builtin_amdgcn_mfma_f32_16x16x32_f16(al[chl], bh, acc[cg], 0, 0, 0);
      }
    }
    __syncthreads();
    STAGE(1);
    __syncthreads();
#pragma unroll
    for (int chl = 0; chl < 2; chl++) {
#pragma unroll
      for (int cg = 0; cg < 8; cg++) {
        int lo = (cg * 16 + c15) * 72 + chl * 32 + q * 8;
        half8 bh = *(const half8*)&BshH[lo];
        half8 bl = *(const half8*)&BshL[lo];
        acc[cg] = __builtin_amdgcn_mfma_f32_16x16x32_f16(ah[2 + chl], bh, acc[cg], 0, 0, 0);
        acc[cg] = __builtin_amdgcn_mfma_f32_16x16x32_f16(ah[2 + chl], bl, acc[cg], 0, 0, 0);
        acc[cg] = __builtin_amdgcn_mfma_f32_16x16x32_f16(al[2 + chl], bh, acc[cg], 0, 0, 0);
      }
    }

#pragma unroll
    for (int cg = 0; cg < 8; cg++) {
      float basec = SDv + smv[cg];
#pragma unroll
      for (int r = 0; r < 4; r++)
        Dw[w][q * 4 + r][cg * 16 + c15] = snr[r] + basec - 2.0f * acc[cg][r];
    }
    if (it == 0) {
#pragma unroll
      for (int jj = 0; jj < 8; jj++) {
        float4 dv = *(const float4*)&Dw[w][r_sel][jj * 16 + sl * 4];
        int ib = m0 + jj * 16 + sl * 4;
        insert10(ld, li, dv.x, ib + 0);
        insert10(ld, li, dv.y, ib + 1);
        insert10(ld, li, dv.z, ib + 2);
        insert10(ld, li, dv.w, ib + 3);
      }
    } else {
      bool any = false;
#pragma unroll
      for (int jj = 0; jj < 8; jj++) {
        float4 dv = *(const float4*)&Dw[w][r_sel][jj * 16 + sl * 4];
        any = any || (dv.x <= tauR) || (dv.y <= tauR) || (dv.z <= tauR) || (dv.w <= tauR);
      }
      if (any) {
#pragma unroll
        for (int jj = 0; jj < 8; jj++) {
          float4 dv = *(const float4*)&Dw[w][r_sel][jj * 16 + sl * 4];
          int ib = m0 + jj * 16 + sl * 4;
          if (dv.x <= tauR) insert10(ld, li, dv.x, ib + 0);
          if (dv.y <= tauR) insert10(ld, li, dv.y, ib + 1);
          if (dv.z <= tauR) insert10(ld, li, dv.z, ib + 2);
          if (dv.w <= tauR) insert10(ld, li, dv.w, ib + 3);
        }
      }
    }
    tauW[w][r_sel][sl] = ld[9];
    float4 tv = *(const float4*)&tauW[w][r_sel][0];
    tauR = fminf(fminf(tv.x, tv.y), fminf(tv.z, tv.w));

    u = u_next; m0 = u_next * 128;
  }

#pragma unroll
  for (int j = 0; j < 10; j++) {
    Dw[w][r_sel][sl * 10 + j] = ld[j];
    Dw[w][r_sel][40 + sl * 10 + j] = __int_as_float(li[j]);
  }
  if (L < 16) {
    float fd[10]; int fi[10];
#pragma unroll
    for (int j = 0; j < 10; j++) { fd[j] = 1e30f; fi[j] = 0x7fffffff; }
    for (int x = 0; x < 40; x++)
      insert10(fd, fi, Dw[w][L][x], __float_as_int(Dw[w][L][40 + x]));
    size_t row = (size_t)b * 2048 + rc0 + L;
#pragma unroll
    for (int j = 0; j < 10; j++) {
      pd[(row * 4 + h) * 10 + j] = fd[j];
      pi[(row * 4 + h) * 10 + j] = fi[j];
    }
  }
}

// ---------------- K4b: merge the 4 quarter-lists (compact rows) ----------------
__global__ __launch_bounds__(256) void k_knn_merge(const float* __restrict__ pd, const int* __restrict__ pi,
                                                   int* __restrict__ knnc) {
  size_t row = blockIdx.x * 256 + threadIdx.x;
  float ld[10]; int li[10];
#pragma unroll
  for (int jj = 0; jj < 10; jj++) { ld[jj] = pd[row * 40 + jj]; li[jj] = pi[row * 40 + jj]; }
#pragma unroll
  for (int jj = 10; jj < 40; jj++) insert10(ld, li, pd[row * 40 + jj], pi[row * 40 + jj]);
#pragma unroll
  for (int jj = 0; jj < 10; jj++) knnc[row * 10 + jj] = li[jj];
}

// ---------------- K5: Q' = g*Q for all rows; P' = g*(P+cb)+bt only for FPS rows ----------
__global__ __launch_bounds__(256, 2) void k_pq_mfma(const _Float16* __restrict__ XH, const _Float16* __restrict__ XL,
    const _Float16* __restrict__ WPh, const _Float16* __restrict__ WPl,
    const _Float16* __restrict__ WQh, const _Float16* __restrict__ WQl,
    const int* __restrict__ fps, const float* __restrict__ g, const float* __restrict__ cb,
    const float* __restrict__ bt, float* __restrict__ Pc, float* __restrict__ Qp) {
  const int b = blockIdx.z;
  const int t = threadIdx.x, w = t >> 6, L = t & 63;
  const int c15 = L & 15, q = L >> 4;
  const int ow = blockIdx.y * 128 + (w >> 1) * 64;
  const size_t bofs = (size_t)b * NPNT;
  f32x4 zz = {0.0f, 0.0f, 0.0f, 0.0f};

  {
    const int nw = blockIdx.x * 32 + (w & 1) * 16;
    f32x4 accQ[4];
#pragma unroll
    for (int cg = 0; cg < 4; cg++) accQ[cg] = zz;
    const _Float16* ap  = XH + (bofs + nw + c15) * 256 + q * 8;
    const _Float16* apl = XL + (bofs + nw + c15) * 256 + q * 8;
#pragma unroll
    for (int ch = 0; ch < 8; ch++) {
      half8 a_h = *(const half8*)(ap + ch * 32);
      half8 a_l = *(const half8*)(apl + ch * 32);
#pragma unroll
      for (int cg = 0; cg < 4; cg++) {
        size_t wb = (size_t)(ow + cg * 16 + c15) * 256 + ch * 32 + q * 8;
        half8 bqh = *(const half8*)(WQh + wb);
        half8 bql = *(const half8*)(WQl + wb);
        accQ[cg] = __builtin_amdgcn_mfma_f32_16x16x32_f16(a_h, bqh, accQ[cg], 0, 0, 0);
        accQ[cg] = __builtin_amdgcn_mfma_f32_16x16x32_f16(a_h, bql, accQ[cg], 0, 0, 0);
        accQ[cg] = __builtin_amdgcn_mfma_f32_16x16x32_f16(a_l, bqh, accQ[cg], 0, 0, 0);
      }
    }
#pragma unroll
    for (int cg = 0; cg < 4; cg++) {
      int o = ow + cg * 16 + c15;
      float gg = g[o];
#pragma unroll
      for (int r = 0; r < 4; r++) {
        Qp[(bofs + nw + q * 4 + r) * 256 + o] = gg * accQ[cg][r];
      }
    }
  }

  if (blockIdx.x < 64) {
    const int m0 = blockIdx.x * 32 + (w & 1) * 16;
    const int jst = m0 >> 7;
    const int pbase = m0 & 127;
    const int nsrc = fps[b * 16 + jst] * 128 + pbase;
    f32x4 accP[4];
#pragma unroll
    for (int cg = 0; cg < 4; cg++) accP[cg] = zz;
    const _Float16* ap  = XH + (bofs + nsrc + c15) * 256 + q * 8;
    const _Float16* apl = XL + (bofs + nsrc + c15) * 256 + q * 8;
#pragma unroll
    for (int ch = 0; ch < 8; ch++) {
      half8 a_h = *(const half8*)(ap + ch * 32);
      half8 a_l = *(const half8*)(apl + ch * 32);
#pragma unroll
      for (int cg = 0; cg < 4; cg++) {
        size_t wb = (size_t)(ow + cg * 16 + c15) * 256 + ch * 32 + q * 8;
        half8 bph = *(const half8*)(WPh + wb);
        half8 bpl = *(const half8*)(WPl + wb);
        accP[cg] = __builtin_amdgcn_mfma_f32_16x16x32_f16(a_h, bph, accP[cg], 0, 0, 0);
        accP[cg] = __builtin_amdgcn_mfma_f32_16x16x32_f16(a_h, bpl, accP[cg], 0, 0, 0);
        accP[cg] = __builtin_amdgcn_mfma_f32_16x16x32_f16(a_l, bph, accP[cg], 0, 0, 0);
      }
    }
#pragma unroll
    for (int cg = 0; cg < 4; cg++) {
      int o = ow + cg * 16 + c15;
      float gg = g[o], bb = cb[o], bo = bt[o];
#pragma unroll
      for (int r = 0; r < 4; r++) {
        Pc[(((size_t)b * 16 + jst) * 128 + pbase + q * 4 + r) * 256 + o] =
            fmaf(gg, accP[cg][r] + bb, bo);
      }
    }
  }
}

// ---------------- K6: build im2col E from compact P'/knnc + Q' ----------------
__global__ __launch_bounds__(256) void k_build_E(const float* __restrict__ Pc, const float* __restrict__ Qp,
    const int* __restrict__ knnc, float* __restrict__ E) {
  int pp = blockIdx.x, j = blockIdx.y, b = blockIdx.z;
  int t = threadIdx.x;
  float v[3];
#pragma unroll
  for (int dp = 0; dp < 3; dp++) {
    int p = 2 * pp - 1 + dp;
    float val = 0.0f;
    if (p >= 0 && p < 128) {
      size_t m = ((size_t)b * 16 + j) * 128 + p;
      float pv = Pc[m * 256 + t];
      const int* id = &knnc[m * 10];
      float mx = 0.0f;
#pragma unroll
      for (int k = 0; k < 10; k++) {
        float qv = Qp[((size_t)b * NPNT + id[k]) * 256 + t];
        float h = pv + qv;
        mx = h > mx ? h : mx;
      }
      val = mx;
    }
    v[dp] = val;
  }
  size_t base = ((size_t)(b * 16 + j) * 64 + pp) * 768;
  E[base + 3 * t + 0] = v[0];
  E[base + 3 * t + 1] = v[1];
  E[base + 3 * t + 2] = v[2];
}

// ---------------- K7: downsample GEMM ----------------
__global__ __launch_bounds__(256) void k_ds_gemm(const float* __restrict__ Wd, const float* __restrict__ E,
    const float* __restrict__ cb, const float* __restrict__ g, const float* __restrict__ bt,
    float* __restrict__ out1) {
  int j0 = blockIdx.x * 64, o0 = blockIdx.y * 64, b = blockIdx.z;
  int t = threadIdx.x;
  __shared__ float A[32][68];
  __shared__ float Bs[32][68];
  float acc[4][4];
#pragma unroll
  for (int i = 0; i < 4; i++)
#pragma unroll
    for (int j = 0; j < 4; j++) acc[i][j] = 0.0f;
  int tj = t & 15, to = t >> 4;
  for (int kc = 0; kc < 768; kc += 32) {
    {
      int ol = t >> 2, q = t & 3;
      const float* src = &Wd[(size_t)(o0 + ol) * 768 + kc + q * 8];
      float4 v0 = *(const float4*)src, v1 = *(const float4*)(src + 4);
      int cc = q * 8;
      A[cc+0][ol] = v0.x; A[cc+1][ol] = v0.y; A[cc+2][ol] = v0.z; A[cc+3][ol] = v0.w;
      A[cc+4][ol] = v1.x; A[cc+5][ol] = v1.y; A[cc+6][ol] = v1.z; A[cc+7][ol] = v1.w;
    }
    {
      int jl = t >> 2, q = t & 3;
      const float* src = &E[((size_t)b * 1024 + j0 + jl) * 768 + kc + q * 8];
      float4 v0 = *(const float4*)src, v1 = *(const float4*)(src + 4);
      int cc = q * 8;
      Bs[cc+0][jl] = v0.x; Bs[cc+1][jl] = v0.y; Bs[cc+2][jl] = v0.z; Bs[cc+3][jl] = v0.w;
      Bs[cc+4][jl] = v1.x; Bs[cc+5][jl] = v1.y; Bs[cc+6][jl] = v1.z; Bs[cc+7][jl] = v1.w;
    }
    __syncthreads();
#pragma unroll 4
    for (int k = 0; k < 32; k++) {
      float4 a = *(const float4*)&A[k][to * 4];
      float4 bv = *(const float4*)&Bs[k][tj * 4];
      float av[4] = {a.x, a.y, a.z, a.w};
      float bb[4] = {bv.x, bv.y, bv.z, bv.w};
#pragma unroll
      for (int i = 0; i < 4; i++)
#pragma unroll
        for (int j = 0; j < 4; j++)
          acc[i][j] = fmaf(av[i], bb[j], acc[i][j]);
    }
    __syncthreads();
  }
#pragma unroll
  for (int i = 0; i < 4; i++) {
    int o = o0 + to * 4 + i;
    float gg = g[o], bb = cb[o], bo = bt[o];
    float4 v;
    float x0 = fmaf(gg, acc[i][0] + bb, bo); v.x = x0 > 0.0f ? x0 : 0.0f;
    float x1 = fmaf(gg, acc[i][1] + bb, bo); v.y = x1 > 0.0f ? x1 : 0.0f;
    float x2 = fmaf(gg, acc[i][2] + bb, bo); v.z = x2 > 0.0f ? x2 : 0.0f;
    float x3 = fmaf(gg, acc[i][3] + bb, bo); v.w = x3 > 0.0f ? x3 : 0.0f;
    *(float4*)&out1[((size_t)b * 256 + o) * 1024 + j0 + tj * 4] = v;
  }
}

extern "C" void kernel_launch(void* const* d_in, const int* in_sizes, int n_in,
                              void* d_out, int out_size, void* d_ws, size_t ws_size,
                              hipStream_t stream) {
  (void)in_sizes; (void)n_in; (void)out_size; (void)ws_size;
  const float* sf    = (const float*)d_in[0];
  const float* df    = (const float*)d_in[1];
  const float* coor  = (const float*)d_in[2];
  const float* d2sw  = (const float*)d_in[3];
  const float* d2sb  = (const float*)d_in[4];
  const float* d2sg  = (const float*)d_in[5];
  const float* d2sbt = (const float*)d_in[6];
  const float* spW   = (const float*)d_in[7];
  const float* spb   = (const float*)d_in[8];
  const float* spg   = (const float*)d_in[9];
  const float* spbt  = (const float*)d_in[10];
  const float* dnW   = (const float*)d_in[11];
  const float* dnb   = (const float*)d_in[12];
  const float* dng   = (const float*)d_in[13];
  const float* dnbt  = (const float*)d_in[14];
  const float* dsw   = (const float*)d_in[15];
  const float* dsb   = (const float*)d_in[16];
  const float* dsg   = (const float*)d_in[17];
  const float* dsbt  = (const float*)d_in[18];

  float* ws   = (float*)d_ws;
  float* Pc   = ws + OFF_P;
  float* Qp   = ws + OFF_Q;
  float* SQD  = ws + OFF_SQD;
  float* SPFD = ws + OFF_SPFD;
  float* XS   = ws + OFF_XS;
  float* PS   = ws + OFF_PS;
  float* QS   = ws + OFF_QS;
  int*   KNNC = (int*)(ws + OFF_KNN);
  int*   IDXS = (int*)(ws + OFF_IDXS);
  int*   FPS  = (int*)(ws + OFF_FPS);
  float* SD   = ws + OFF_SD;
  _Float16* XT2H = (_Float16*)(ws + OFF_XT);
  _Float16* XT2L = XT2H + (size_t)4 * NPNT * 256;
  float* E = ws + OFF_XT;
  _Float16* WPh = (_Float16*)(ws + OFF_WSP);
  _Float16* WPl = WPh + 65536;
  _Float16* WQh = WPh + 131072;
  _Float16* WQl = WPh + 196608;
  // compact quarter-lists alias the Q region (consumed before k_pq_mfma writes Q')
  float* PDL = ws + OFF_Q;
  int*   PIL = (int*)(ws + OFF_Q + 327680);

  float* out0 = (float*)d_out;
  float* out1 = out0 + 16384;
  float* out2 = out1 + 1048576;

  k_split256<<<dim3(4, 64), 256, 0, stream>>>(df, sf, XT2H, XT2L, SQD);
  k_splitW<<<dim3(256), 256, 0, stream>>>(dnW, WPh, WPl, WQh, WQl);
  k_d2s<<<dim3(4, 2, 32), 256, 0, stream>>>(df, d2sw, d2sb, d2sg, d2sbt, SPFD);
  k_fps<<<dim3(4), 128, 0, stream>>>(coor, FPS, out2);
  k_sparse_graph<<<dim3(4), 256, 0, stream>>>(sf, SPFD, XS, IDXS, SD);
  k_sparse_pq<<<dim3(128), 256, 0, stream>>>(XS, spW, PS, QS);
  k_sparse_cg<<<dim3(4, 16), 256, 0, stream>>>(PS, QS, IDXS, FPS, spg, spb, spbt, out0);
  k_knn_mfma<<<dim3(4, 32, 4), 256, 0, stream>>>(XT2H, XT2L, SQD, SD, FPS, PDL, PIL);
  k_knn_merge<<<dim3(32), 256, 0, stream>>>(PDL, PIL, KNNC);
  k_pq_mfma<<<dim3(128, 2, 4), 256, 0, stream>>>(XT2H, XT2L, WPh, WPl, WQh, WQl,
                                                 FPS, dng, dnb, dnbt, Pc, Qp);
  k_build_E<<<dim3(64, 16, 4), 256, 0, stream>>>(Pc, Qp, KNNC, E);
  k_ds_gemm<<<dim3(16, 4, 4), 256, 0, stream>>>(dsw, E, dsb, dsg, dsbt, out1);
}